// Round 1
// baseline (397.842 us; speedup 1.0000x reference)
//
#include <hip/hip_runtime.h>
#include <cstdint>

#define B_   32
#define C_   512
#define N_   1024
#define G_   32
#define CG_  16

typedef unsigned short u16;

static constexpr float kEps   = 1e-5f;
static constexpr float kScale = 0.04419417382415922f;  // 512^-0.5

using f32x4  = __attribute__((ext_vector_type(4))) float;
using short8 = __attribute__((ext_vector_type(8))) short;

__device__ __forceinline__ u16 f2bf(float f) {
  uint32_t u = __builtin_bit_cast(uint32_t, f);
  u += 0x7fffu + ((u >> 16) & 1u);   // RNE
  return (u16)(u >> 16);
}
__device__ __forceinline__ float bf2f(u16 h) {
  return __builtin_bit_cast(float, (uint32_t)h << 16);
}

// async global->LDS, 16B per lane. LDS dest must be wave-uniform base (HW adds lane*16).
__device__ __forceinline__ void gload16(const void* g, void* lds) {
  __builtin_amdgcn_global_load_lds(
      (__attribute__((address_space(1))) void*)(uintptr_t)g,
      (__attribute__((address_space(3))) void*)(uint32_t)(uintptr_t)lds,
      16, 0, 0);
}

// ---------------- weights: Wt[m][o][c] = bf16(W[c][o]) ----------------
__global__ __launch_bounds__(256) void wt_kernel(
    const float* __restrict__ Wq, const float* __restrict__ Wk,
    const float* __restrict__ Wv, const float* __restrict__ Wn,
    u16* __restrict__ Wt) {
  const int idx = blockIdx.x * 256 + threadIdx.x;   // 4*262144 total
  const int m = idx >> 18;
  const int e = idx & 262143;
  const int o = e >> 9, c = e & 511;
  const float* W = (m == 0) ? Wq : (m == 1) ? Wk : (m == 2) ? Wv : Wn;
  Wt[idx] = f2bf(W[c * 512 + o]);
}

// ---------------- groupnorm stats per (b,g): contiguous 16384 floats ----------------
__global__ __launch_bounds__(256) void gn_stats(const float* __restrict__ x,
                                                float* __restrict__ stats) {
  __shared__ float red[8];
  const int bg = blockIdx.x;
  const float4* p4 = (const float4*)(x + (size_t)bg * (CG_ * N_));
  float s = 0.f, s2 = 0.f;
  for (int i = threadIdx.x; i < (CG_ * N_) / 4; i += 256) {
    const float4 v = p4[i];
    s  += v.x + v.y + v.z + v.w;
    s2 += v.x * v.x + v.y * v.y + v.z * v.z + v.w * v.w;
  }
#pragma unroll
  for (int o = 32; o; o >>= 1) { s += __shfl_xor(s, o); s2 += __shfl_xor(s2, o); }
  const int lane = threadIdx.x & 63, w = threadIdx.x >> 6;
  if (lane == 0) { red[w] = s; red[4 + w] = s2; }
  __syncthreads();
  if (threadIdx.x == 0) {
    s  = red[0] + red[1] + red[2] + red[3];
    s2 = red[4] + red[5] + red[6] + red[7];
    const float inv = 1.0f / (CG_ * N_);
    const float mean = s * inv;
    const float var  = s2 * inv - mean * mean;
    stats[bg * 2]     = mean;
    stats[bg * 2 + 1] = rsqrtf(var + kEps);
  }
}

// ---------------- normalize + transpose: Hn[b][n][c] = bf16((x[b][c][n]-mu)*rstd) ----
__global__ __launch_bounds__(256) void gn_apply(const float* __restrict__ x,
                                                const float* __restrict__ stats,
                                                u16* __restrict__ Hn) {
  __shared__ float tile[64][65];
  const int b = blockIdx.z, c0 = blockIdx.y * 64, n0 = blockIdx.x * 64;
  const int tx = threadIdx.x & 15, ty = threadIdx.x >> 4;
#pragma unroll
  for (int rr = 0; rr < 64; rr += 16) {
    const int c = c0 + ty + rr;
    const float mean = stats[(b * G_ + (c >> 4)) * 2];
    const float rstd = stats[(b * G_ + (c >> 4)) * 2 + 1];
    const float4 v = *(const float4*)(x + ((size_t)(b * C_ + c)) * N_ + n0 + tx * 4);
    tile[ty + rr][tx * 4 + 0] = (v.x - mean) * rstd;
    tile[ty + rr][tx * 4 + 1] = (v.y - mean) * rstd;
    tile[ty + rr][tx * 4 + 2] = (v.z - mean) * rstd;
    tile[ty + rr][tx * 4 + 3] = (v.w - mean) * rstd;
  }
  __syncthreads();
#pragma unroll
  for (int rr = 0; rr < 64; rr += 16) {
    const int n = n0 + ty + rr;
    ushort4 o;
    o.x = f2bf(tile[tx * 4 + 0][ty + rr]);
    o.y = f2bf(tile[tx * 4 + 1][ty + rr]);
    o.z = f2bf(tile[tx * 4 + 2][ty + rr]);
    o.w = f2bf(tile[tx * 4 + 3][ty + rr]);
    *(ushort4*)(Hn + ((size_t)(b * N_ + n)) * C_ + c0 + tx * 4) = o;
  }
}

// ---------------- shared GEMM core: D[m][n] = sum_k A[m][k]*B[n][k] (both row-major, ld=Ktot)
// 128x128 tile, BK=32, 256 threads = 4 waves (2x2), wave does 4x4 frags of 16x16x32.
__device__ __forceinline__ void gemm_core(
    const u16* __restrict__ A, const u16* __restrict__ B,
    int Ktot, int m0, int n0,
    u16* Alds, u16* Blds, f32x4 acc[4][4]) {
  const int tid  = threadIdx.x;
  const int lane = tid & 63;
  const int wid  = tid >> 6;
  const int wm = wid >> 1, wn = wid & 1;
  const int lrow = lane >> 2, lk8 = (lane & 3) * 8;
  const int q0 = wid * 2, q1 = q0 + 1;

  const u16* Ag0 = A + (size_t)(m0 + q0 * 16 + lrow) * Ktot + lk8;
  const u16* Ag1 = A + (size_t)(m0 + q1 * 16 + lrow) * Ktot + lk8;
  const u16* Bg0 = B + (size_t)(n0 + q0 * 16 + lrow) * Ktot + lk8;
  const u16* Bg1 = B + (size_t)(n0 + q1 * 16 + lrow) * Ktot + lk8;
  char* Al0 = (char*)Alds + q0 * 1024;
  char* Al1 = (char*)Alds + q1 * 1024;
  char* Bl0 = (char*)Blds + q0 * 1024;
  char* Bl1 = (char*)Blds + q1 * 1024;

  const int arow = lane & 15, akb = (lane >> 4) * 8;
  const u16* Afr = Alds + (wm * 64 + arow) * 32 + akb;
  const u16* Bfr = Blds + (wn * 64 + arow) * 32 + akb;

  for (int k = 0; k < Ktot; k += 32) {
    gload16(Ag0, Al0); gload16(Ag1, Al1);
    gload16(Bg0, Bl0); gload16(Bg1, Bl1);
    Ag0 += 32; Ag1 += 32; Bg0 += 32; Bg1 += 32;
    __syncthreads();   // drains vmcnt before barrier -> LDS tile complete
    short8 a[4], b[4];
#pragma unroll
    for (int i = 0; i < 4; ++i) a[i] = *(const short8*)(Afr + i * 512);
#pragma unroll
    for (int j = 0; j < 4; ++j) b[j] = *(const short8*)(Bfr + j * 512);
#pragma unroll
    for (int i = 0; i < 4; ++i)
#pragma unroll
      for (int j = 0; j < 4; ++j)
        acc[i][j] = __builtin_amdgcn_mfma_f32_16x16x32_bf16(a[i], b[j], acc[i][j], 0, 0, 0);
    __syncthreads();   // protect LDS reuse next K-step
  }
}

// D fragment mapping (m89-verified): col = lane&15, row = (lane>>4)*4 + reg.
// Store at Out[col*LDC + row] -> per-lane 4 consecutive elements (ushort4).
__global__ __launch_bounds__(256) void gemm_bt(
    const u16* __restrict__ A, long long sAz,
    const u16* __restrict__ B, long long sBz,
    u16* __restrict__ Out, long long sOz,
    int Ktot, int LDC, float scale,
    const float* __restrict__ bias, int biasMode) {
  __shared__ u16 Alds[128 * 32];
  __shared__ u16 Blds[128 * 32];
  const int z = blockIdx.z;
  A += (size_t)z * sAz;
  B += (size_t)z * sBz;
  u16* O = Out + (size_t)z * sOz;
  const int m0 = blockIdx.y * 128, n0 = blockIdx.x * 128;
  f32x4 acc[4][4] = {};
  gemm_core(A, B, Ktot, m0, n0, Alds, Blds, acc);

  const int lane = threadIdx.x & 63, wid = threadIdx.x >> 6;
  const int wm = wid >> 1, wn = wid & 1;
#pragma unroll
  for (int i = 0; i < 4; ++i) {
    const int rowg = m0 + wm * 64 + i * 16 + ((lane >> 4) * 4);
    float b0 = 0.f, b1 = 0.f, b2 = 0.f, b3 = 0.f;
    if (biasMode == 1) {
      const float4 bv = *(const float4*)(bias + rowg);
      b0 = bv.x; b1 = bv.y; b2 = bv.z; b3 = bv.w;
    }
#pragma unroll
    for (int j = 0; j < 4; ++j) {
      const int colg = n0 + wn * 64 + j * 16 + (lane & 15);
      const float bc = (biasMode == 2) ? bias[colg] : 0.0f;
      const f32x4 v = acc[i][j];
      ushort4 st;
      st.x = f2bf(v[0] * scale + b0 + bc);
      st.y = f2bf(v[1] * scale + b1 + bc);
      st.z = f2bf(v[2] * scale + b2 + bc);
      st.w = f2bf(v[3] * scale + b3 + bc);
      *(ushort4*)(O + (size_t)colg * LDC + rowg) = st;
    }
  }
}

// final: D[n][o] = sum_c H2[n][c]*Wnt[o][c]; out[b][o][n] = x + D + bn[o]  (fp32)
__global__ __launch_bounds__(256) void gemm_bt_final(
    const u16* __restrict__ A, const u16* __restrict__ Bw,
    const float* __restrict__ x, const float* __restrict__ bn,
    float* __restrict__ Out, int Ktot) {
  __shared__ u16 Alds[128 * 32];
  __shared__ u16 Blds[128 * 32];
  const int z = blockIdx.z;
  const u16*   Ab = A + (size_t)z * ((size_t)N_ * C_);
  const float* xb = x + (size_t)z * ((size_t)C_ * N_);
  float*       Ob = Out + (size_t)z * ((size_t)C_ * N_);
  const int m0 = blockIdx.y * 128, n0 = blockIdx.x * 128;
  f32x4 acc[4][4] = {};
  gemm_core(Ab, Bw, Ktot, m0, n0, Alds, Blds, acc);

  const int lane = threadIdx.x & 63, wid = threadIdx.x >> 6;
  const int wm = wid >> 1, wn = wid & 1;
#pragma unroll
  for (int i = 0; i < 4; ++i) {
    const int rowg = m0 + wm * 64 + i * 16 + ((lane >> 4) * 4);   // n
#pragma unroll
    for (int j = 0; j < 4; ++j) {
      const int colg = n0 + wn * 64 + j * 16 + (lane & 15);       // o
      const float bc = bn[colg];
      const size_t off = (size_t)colg * N_ + rowg;
      const float4 xv = *(const float4*)(xb + off);
      const f32x4 v = acc[i][j];
      float4 ov;
      ov.x = xv.x + v[0] + bc;
      ov.y = xv.y + v[1] + bc;
      ov.z = xv.z + v[2] + bc;
      ov.w = xv.w + v[3] + bc;
      *(float4*)(Ob + off) = ov;
    }
  }
}

// ---------------- row softmax in-place on bf16 P[b*N+n][1024] ----------------
__global__ __launch_bounds__(256) void softmax_rows(u16* __restrict__ P) {
  __shared__ float red[8];
  u16* p = P + (size_t)blockIdx.x * 1024;
  const int tid = threadIdx.x;
  const ushort4 u = ((const ushort4*)p)[tid];
  const float v0 = bf2f(u.x), v1 = bf2f(u.y), v2 = bf2f(u.z), v3 = bf2f(u.w);
  float m = fmaxf(fmaxf(v0, v1), fmaxf(v2, v3));
#pragma unroll
  for (int o = 32; o; o >>= 1) m = fmaxf(m, __shfl_xor(m, o));
  const int lane = tid & 63, w = tid >> 6;
  if (lane == 0) red[w] = m;
  __syncthreads();
  m = fmaxf(fmaxf(red[0], red[1]), fmaxf(red[2], red[3]));
  const float e0 = __expf(v0 - m), e1 = __expf(v1 - m),
              e2 = __expf(v2 - m), e3 = __expf(v3 - m);
  float s = e0 + e1 + e2 + e3;
#pragma unroll
  for (int o = 32; o; o >>= 1) s += __shfl_xor(s, o);
  if (lane == 0) red[4 + w] = s;
  __syncthreads();
  s = red[4] + red[5] + red[6] + red[7];
  const float inv = 1.0f / s;
  ushort4 o4;
  o4.x = f2bf(e0 * inv); o4.y = f2bf(e1 * inv);
  o4.z = f2bf(e2 * inv); o4.w = f2bf(e3 * inv);
  ((ushort4*)p)[tid] = o4;
}

__global__ void sentinel_kernel(float* out, int n, float v) {
  const int i = blockIdx.x * blockDim.x + threadIdx.x;
  if (i < n) out[i] = v;
}

extern "C" void kernel_launch(void* const* d_in, const int* in_sizes, int n_in,
                              void* d_out, int out_size, void* d_ws, size_t ws_size,
                              hipStream_t stream) {
  const float* x  = (const float*)d_in[0];
  const float* Wq = (const float*)d_in[1];
  const float* bq = (const float*)d_in[2];
  const float* Wk = (const float*)d_in[3];
  const float* bk = (const float*)d_in[4];
  const float* Wv = (const float*)d_in[5];
  const float* bv = (const float*)d_in[6];
  const float* Wn = (const float*)d_in[7];
  const float* bn = (const float*)d_in[8];
  float* out = (float*)d_out;

  char* ws = (char*)d_ws;
  size_t off = 0;
  u16* Wt = (u16*)(ws + off);      off += (size_t)4 * 512 * 512 * 2;   // bf16 W^T x4
  float* stats = (float*)(ws + off); off += 2048 * 4;                  // mean/rstd
  const size_t bnc = (size_t)B_ * N_ * C_;
  u16* Hn = (u16*)(ws + off); off += bnc * 2;          // [b][n][c]
  u16* Qb = (u16*)(ws + off); off += bnc * 2;          // [b][n][c]
  u16* Kb = (u16*)(ws + off); off += bnc * 2;          // [b][m][c]
  u16* Vt = (u16*)(ws + off); off += bnc * 2;          // [b][c][m]
  u16* P  = (u16*)(ws + off); off += (size_t)B_ * N_ * N_ * 2;  // [b][n][m]
  u16* H2 = (u16*)(ws + off); off += bnc * 2;          // [b][n][c]

  if (ws_size < off) {
    const float v = 1.0e6f + (float)(ws_size >> 20);   // absmax ~ 1e6+MB -> diagnosable
    sentinel_kernel<<<(out_size + 255) / 256, 256, 0, stream>>>(out, out_size, v);
    return;
  }

  wt_kernel<<<4096, 256, 0, stream>>>(Wq, Wk, Wv, Wn, Wt);
  gn_stats<<<B_ * G_, 256, 0, stream>>>(x, stats);
  gn_apply<<<dim3(N_ / 64, C_ / 64, B_), 256, 0, stream>>>(x, stats, Hn);

  const long long sNC = (long long)N_ * C_;
  const long long sNN = (long long)N_ * N_;
  // Q[n][o]: A=Wq^T (rows o, M'=512), B=Hn (rows n, N'=1024), bias over rows(o)
  gemm_bt<<<dim3(8, 4, B_), 256, 0, stream>>>(Wt,          0, Hn, sNC, Qb, sNC, 512,  512, 1.0f, bq, 1);
  gemm_bt<<<dim3(8, 4, B_), 256, 0, stream>>>(Wt + 262144, 0, Hn, sNC, Kb, sNC, 512,  512, 1.0f, bk, 1);
  // Vt[o][n]: A=Hn (rows n, M'=1024), B=Wv^T (rows o, N'=512), bias over cols(o)
  gemm_bt<<<dim3(4, 8, B_), 256, 0, stream>>>(Hn, sNC, Wt + 2 * 262144, 0, Vt, sNC, 512, 1024, 1.0f, bv, 2);
  // S[n][m]: A=K (rows m, M'=1024), B=Q (rows n, N'=1024), K-dim=512, scaled
  gemm_bt<<<dim3(8, 8, B_), 256, 0, stream>>>(Kb, sNC, Qb, sNC, P, sNN, 512, 1024, kScale, nullptr, 0);
  softmax_rows<<<B_ * N_, 256, 0, stream>>>(P);
  // H2[n][c]: A=Vt (rows c, M'=512), B=P (rows n, N'=1024), K-dim=1024
  gemm_bt<<<dim3(8, 4, B_), 256, 0, stream>>>(Vt, sNC, P, sNN, H2, sNC, 1024, 512, 1.0f, nullptr, 0);
  // out[o][n] = x + H2·Wn^T + bn
  gemm_bt_final<<<dim3(4, 8, B_), 256, 0, stream>>>(H2, Wt + 3 * 262144, x, bn, out, 512);
}

// Round 2
// 343.273 us; speedup vs baseline: 1.1590x; 1.1590x over previous
//
#include <hip/hip_runtime.h>
#include <cstdint>

#define B_   32
#define C_   512
#define N_   1024
#define G_   32
#define CG_  16

typedef unsigned short u16;

static constexpr float kEps   = 1e-5f;
static constexpr float kScale = 0.04419417382415922f;  // 512^-0.5

using f32x4  = __attribute__((ext_vector_type(4))) float;
using short8 = __attribute__((ext_vector_type(8))) short;

__device__ __forceinline__ u16 f2bf(float f) {
  uint32_t u = __builtin_bit_cast(uint32_t, f);
  u += 0x7fffu + ((u >> 16) & 1u);   // RNE
  return (u16)(u >> 16);
}
__device__ __forceinline__ float bf2f(u16 h) {
  return __builtin_bit_cast(float, (uint32_t)h << 16);
}

// async global->LDS, 16B per lane. LDS dest is wave-uniform base (HW adds lane*16).
__device__ __forceinline__ void gload16(const void* g, void* lds) {
  __builtin_amdgcn_global_load_lds(
      (__attribute__((address_space(1))) void*)(uintptr_t)g,
      (__attribute__((address_space(3))) void*)(uint32_t)(uintptr_t)lds,
      16, 0, 0);
}

// bijective XCD-chunked remap (m204): contiguous logical chunk per XCD.
__device__ __forceinline__ uint3 remap_xcd() {
  const int gx = gridDim.x, gy = gridDim.y, gz = gridDim.z;
  const int nwg = gx * gy * gz;
  const int lin = blockIdx.x + gx * (blockIdx.y + gy * blockIdx.z);
  const int q = nwg >> 3, r = nwg & 7;
  const int xcd = lin & 7, pos = lin >> 3;
  int nid = (xcd < r ? xcd * (q + 1) : r * (q + 1) + (xcd - r) * q) + pos;
  uint3 o;
  o.x = nid % gx; nid /= gx;
  o.y = nid % gy; o.z = nid / gy;
  return o;
}

// ---------------- weights: Wt[m][o][c] = bf16(W[c][o]) ----------------
__global__ __launch_bounds__(256) void wt_kernel(
    const float* __restrict__ Wq, const float* __restrict__ Wk,
    const float* __restrict__ Wv, const float* __restrict__ Wn,
    u16* __restrict__ Wt) {
  const int idx = blockIdx.x * 256 + threadIdx.x;   // 4*262144 total
  const int m = idx >> 18;
  const int e = idx & 262143;
  const int o = e >> 9, c = e & 511;
  const float* W = (m == 0) ? Wq : (m == 1) ? Wk : (m == 2) ? Wv : Wn;
  Wt[idx] = f2bf(W[c * 512 + o]);
}

// ---------------- groupnorm stats per (b,g): contiguous 16384 floats ----------------
__global__ __launch_bounds__(256) void gn_stats(const float* __restrict__ x,
                                                float* __restrict__ stats) {
  __shared__ float red[8];
  const int bg = blockIdx.x;
  const float4* p4 = (const float4*)(x + (size_t)bg * (CG_ * N_));
  float s = 0.f, s2 = 0.f;
  for (int i = threadIdx.x; i < (CG_ * N_) / 4; i += 256) {
    const float4 v = p4[i];
    s  += v.x + v.y + v.z + v.w;
    s2 += v.x * v.x + v.y * v.y + v.z * v.z + v.w * v.w;
  }
#pragma unroll
  for (int o = 32; o; o >>= 1) { s += __shfl_xor(s, o); s2 += __shfl_xor(s2, o); }
  const int lane = threadIdx.x & 63, w = threadIdx.x >> 6;
  if (lane == 0) { red[w] = s; red[4 + w] = s2; }
  __syncthreads();
  if (threadIdx.x == 0) {
    s  = red[0] + red[1] + red[2] + red[3];
    s2 = red[4] + red[5] + red[6] + red[7];
    const float inv = 1.0f / (CG_ * N_);
    const float mean = s * inv;
    const float var  = s2 * inv - mean * mean;
    stats[bg * 2]     = mean;
    stats[bg * 2 + 1] = rsqrtf(var + kEps);
  }
}

// ---------------- normalize + transpose: Hn[b][n][c] = bf16((x[b][c][n]-mu)*rstd) ----
__global__ __launch_bounds__(256) void gn_apply(const float* __restrict__ x,
                                                const float* __restrict__ stats,
                                                u16* __restrict__ Hn) {
  __shared__ float tile[64][65];
  const int b = blockIdx.z, c0 = blockIdx.y * 64, n0 = blockIdx.x * 64;
  const int tx = threadIdx.x & 15, ty = threadIdx.x >> 4;
#pragma unroll
  for (int rr = 0; rr < 64; rr += 16) {
    const int c = c0 + ty + rr;
    const float mean = stats[(b * G_ + (c >> 4)) * 2];
    const float rstd = stats[(b * G_ + (c >> 4)) * 2 + 1];
    const float4 v = *(const float4*)(x + ((size_t)(b * C_ + c)) * N_ + n0 + tx * 4);
    tile[ty + rr][tx * 4 + 0] = (v.x - mean) * rstd;
    tile[ty + rr][tx * 4 + 1] = (v.y - mean) * rstd;
    tile[ty + rr][tx * 4 + 2] = (v.z - mean) * rstd;
    tile[ty + rr][tx * 4 + 3] = (v.w - mean) * rstd;
  }
  __syncthreads();
#pragma unroll
  for (int rr = 0; rr < 64; rr += 16) {
    const int n = n0 + ty + rr;
    ushort4 o;
    o.x = f2bf(tile[tx * 4 + 0][ty + rr]);
    o.y = f2bf(tile[tx * 4 + 1][ty + rr]);
    o.z = f2bf(tile[tx * 4 + 2][ty + rr]);
    o.w = f2bf(tile[tx * 4 + 3][ty + rr]);
    *(ushort4*)(Hn + ((size_t)(b * N_ + n)) * C_ + c0 + tx * 4) = o;
  }
}

// ---------------- GEMM core v2: D[m][n] = sum_k A[m][k]*B[n][k], 128x128 tile, BK=64.
// LDS tile [128][64] bf16 (128B rows), XOR-swizzled: logical 16B-block cb of row r is
// stored at phys cb ^ (r&7). global_load_lds writes linearly, so the swizzle is applied
// on the per-lane GLOBAL source column (both-sides rule, m104/m231).
__device__ __forceinline__ void gemm_core(
    const u16* __restrict__ A, const u16* __restrict__ B,
    int Ktot, int m0, int n0,
    u16* Alds, u16* Blds, f32x4 acc[4][4]) {
  const int tid  = threadIdx.x;
  const int lane = tid & 63;
  const int wid  = tid >> 6;
  const int wm = wid >> 1, wn = wid & 1;

  // staging: wave wid stages rows wid*32 .. wid*32+31 (4 gloads x 8 rows each)
  const int srow = wid * 32 + (lane >> 3);             // +g*8 per gload
  const int scb  = (lane & 7) ^ (lane >> 3);           // pre-swizzled source col16
  const u16* Ag = A + (size_t)(m0 + srow) * Ktot + scb * 8;
  const u16* Bg = B + (size_t)(n0 + srow) * Ktot + scb * 8;
  char* Alb = (char*)Alds + wid * 4096;
  char* Blb = (char*)Blds + wid * 4096;

  // read side: logical row r = w*64 + i*16 + (lane&15); (r&7) == (lane&7)
  const int arow = lane & 15;
  const int g4   = lane >> 4;          // 0..3
  const int rx   = lane & 7;

  for (int k = 0; k < Ktot; k += 64) {
#pragma unroll
    for (int g = 0; g < 4; ++g) {
      gload16(Ag + (size_t)(g * 8) * Ktot, Alb + g * 1024);
      gload16(Bg + (size_t)(g * 8) * Ktot, Blb + g * 1024);
    }
    Ag += 64; Bg += 64;
    __syncthreads();   // drains vmcnt -> LDS tile complete
#pragma unroll
    for (int kk = 0; kk < 2; ++kk) {
      const int pc = ((kk * 4 + g4) ^ rx) * 16;        // swizzled phys byte col
      short8 a[4], b[4];
#pragma unroll
      for (int i = 0; i < 4; ++i) {
        const int ra = wm * 64 + i * 16 + arow;
        const int rb = wn * 64 + i * 16 + arow;
        a[i] = *(const short8*)((const char*)Alds + ra * 128 + pc);
        b[i] = *(const short8*)((const char*)Blds + rb * 128 + pc);
      }
#pragma unroll
      for (int i = 0; i < 4; ++i)
#pragma unroll
        for (int j = 0; j < 4; ++j)
          acc[i][j] = __builtin_amdgcn_mfma_f32_16x16x32_bf16(a[i], b[j], acc[i][j], 0, 0, 0);
    }
    __syncthreads();   // protect LDS reuse next K-step
  }
}

// D fragment mapping (m89-verified): col = lane&15, row = (lane>>4)*4 + reg.
// Store at Out[col*LDC + row] -> per-lane 4 consecutive elements (ushort4).
__global__ __launch_bounds__(256) void gemm_bt(
    const u16* __restrict__ A, long long sAz,
    const u16* __restrict__ B, long long sBz,
    u16* __restrict__ Out, long long sOz,
    int Ktot, int LDC, float scale,
    const float* __restrict__ bias, int biasMode) {
  __shared__ u16 Alds[128 * 64];
  __shared__ u16 Blds[128 * 64];
  const uint3 bid = remap_xcd();
  const int z = bid.z;
  A += (size_t)z * sAz;
  B += (size_t)z * sBz;
  u16* O = Out + (size_t)z * sOz;
  const int m0 = bid.y * 128, n0 = bid.x * 128;
  f32x4 acc[4][4] = {};
  gemm_core(A, B, Ktot, m0, n0, Alds, Blds, acc);

  const int lane = threadIdx.x & 63, wid = threadIdx.x >> 6;
  const int wm = wid >> 1, wn = wid & 1;
#pragma unroll
  for (int i = 0; i < 4; ++i) {
    const int rowg = m0 + wm * 64 + i * 16 + ((lane >> 4) * 4);
    float b0 = 0.f, b1 = 0.f, b2 = 0.f, b3 = 0.f;
    if (biasMode == 1) {
      const float4 bv = *(const float4*)(bias + rowg);
      b0 = bv.x; b1 = bv.y; b2 = bv.z; b3 = bv.w;
    }
#pragma unroll
    for (int j = 0; j < 4; ++j) {
      const int colg = n0 + wn * 64 + j * 16 + (lane & 15);
      const float bc = (biasMode == 2) ? bias[colg] : 0.0f;
      const f32x4 v = acc[i][j];
      ushort4 st;
      st.x = f2bf(v[0] * scale + b0 + bc);
      st.y = f2bf(v[1] * scale + b1 + bc);
      st.z = f2bf(v[2] * scale + b2 + bc);
      st.w = f2bf(v[3] * scale + b3 + bc);
      *(ushort4*)(O + (size_t)colg * LDC + rowg) = st;
    }
  }
}

// final: D[n][o] = sum_c H2[n][c]*Wnt[o][c]; out[b][o][n] = x + D + bn[o]  (fp32)
__global__ __launch_bounds__(256) void gemm_bt_final(
    const u16* __restrict__ A, const u16* __restrict__ Bw,
    const float* __restrict__ x, const float* __restrict__ bn,
    float* __restrict__ Out, int Ktot) {
  __shared__ u16 Alds[128 * 64];
  __shared__ u16 Blds[128 * 64];
  const uint3 bid = remap_xcd();
  const int z = bid.z;
  const u16*   Ab = A + (size_t)z * ((size_t)N_ * C_);
  const float* xb = x + (size_t)z * ((size_t)C_ * N_);
  float*       Ob = Out + (size_t)z * ((size_t)C_ * N_);
  const int m0 = bid.y * 128, n0 = bid.x * 128;
  f32x4 acc[4][4] = {};
  gemm_core(Ab, Bw, Ktot, m0, n0, Alds, Blds, acc);

  const int lane = threadIdx.x & 63, wid = threadIdx.x >> 6;
  const int wm = wid >> 1, wn = wid & 1;
#pragma unroll
  for (int i = 0; i < 4; ++i) {
    const int rowg = m0 + wm * 64 + i * 16 + ((lane >> 4) * 4);   // n
#pragma unroll
    for (int j = 0; j < 4; ++j) {
      const int colg = n0 + wn * 64 + j * 16 + (lane & 15);       // o
      const float bc = bn[colg];
      const size_t off = (size_t)colg * N_ + rowg;
      const float4 xv = *(const float4*)(xb + off);
      const f32x4 v = acc[i][j];
      float4 ov;
      ov.x = xv.x + v[0] + bc;
      ov.y = xv.y + v[1] + bc;
      ov.z = xv.z + v[2] + bc;
      ov.w = xv.w + v[3] + bc;
      *(float4*)(Ob + off) = ov;
    }
  }
}

// ---------------- row softmax in-place on bf16 P[b*N+n][1024] ----------------
__global__ __launch_bounds__(256) void softmax_rows(u16* __restrict__ P) {
  __shared__ float red[8];
  u16* p = P + (size_t)blockIdx.x * 1024;
  const int tid = threadIdx.x;
  const ushort4 u = ((const ushort4*)p)[tid];
  const float v0 = bf2f(u.x), v1 = bf2f(u.y), v2 = bf2f(u.z), v3 = bf2f(u.w);
  float m = fmaxf(fmaxf(v0, v1), fmaxf(v2, v3));
#pragma unroll
  for (int o = 32; o; o >>= 1) m = fmaxf(m, __shfl_xor(m, o));
  const int lane = tid & 63, w = tid >> 6;
  if (lane == 0) red[w] = m;
  __syncthreads();
  m = fmaxf(fmaxf(red[0], red[1]), fmaxf(red[2], red[3]));
  const float e0 = __expf(v0 - m), e1 = __expf(v1 - m),
              e2 = __expf(v2 - m), e3 = __expf(v3 - m);
  float s = e0 + e1 + e2 + e3;
#pragma unroll
  for (int o = 32; o; o >>= 1) s += __shfl_xor(s, o);
  if (lane == 0) red[4 + w] = s;
  __syncthreads();
  s = red[4] + red[5] + red[6] + red[7];
  const float inv = 1.0f / s;
  ushort4 o4;
  o4.x = f2bf(e0 * inv); o4.y = f2bf(e1 * inv);
  o4.z = f2bf(e2 * inv); o4.w = f2bf(e3 * inv);
  ((ushort4*)p)[tid] = o4;
}

__global__ void sentinel_kernel(float* out, int n, float v) {
  const int i = blockIdx.x * blockDim.x + threadIdx.x;
  if (i < n) out[i] = v;
}

extern "C" void kernel_launch(void* const* d_in, const int* in_sizes, int n_in,
                              void* d_out, int out_size, void* d_ws, size_t ws_size,
                              hipStream_t stream) {
  const float* x  = (const float*)d_in[0];
  const float* Wq = (const float*)d_in[1];
  const float* bq = (const float*)d_in[2];
  const float* Wk = (const float*)d_in[3];
  const float* bk = (const float*)d_in[4];
  const float* Wv = (const float*)d_in[5];
  const float* bv = (const float*)d_in[6];
  const float* Wn = (const float*)d_in[7];
  const float* bn = (const float*)d_in[8];
  float* out = (float*)d_out;

  char* ws = (char*)d_ws;
  size_t off = 0;
  u16* Wt = (u16*)(ws + off);      off += (size_t)4 * 512 * 512 * 2;   // bf16 W^T x4
  float* stats = (float*)(ws + off); off += 2048 * 4;                  // mean/rstd
  const size_t bnc = (size_t)B_ * N_ * C_;
  u16* Hn = (u16*)(ws + off); off += bnc * 2;          // [b][n][c]
  u16* Qb = (u16*)(ws + off); off += bnc * 2;          // [b][n][c]
  u16* Kb = (u16*)(ws + off); off += bnc * 2;          // [b][m][c]
  u16* Vt = (u16*)(ws + off); off += bnc * 2;          // [b][c][m]
  u16* P  = (u16*)(ws + off); off += (size_t)B_ * N_ * N_ * 2;  // [b][n][m]
  u16* H2 = (u16*)(ws + off); off += bnc * 2;          // [b][n][c]

  if (ws_size < off) {
    const float v = 1.0e6f + (float)(ws_size >> 20);   // absmax ~ 1e6+MB -> diagnosable
    sentinel_kernel<<<(out_size + 255) / 256, 256, 0, stream>>>(out, out_size, v);
    return;
  }

  wt_kernel<<<4096, 256, 0, stream>>>(Wq, Wk, Wv, Wn, Wt);
  gn_stats<<<B_ * G_, 256, 0, stream>>>(x, stats);
  gn_apply<<<dim3(N_ / 64, C_ / 64, B_), 256, 0, stream>>>(x, stats, Hn);

  const long long sNC = (long long)N_ * C_;
  const long long sNN = (long long)N_ * N_;
  // Q[n][o]: A=Wq^T (rows o, M'=512), B=Hn (rows n, N'=1024), bias over rows(o)
  gemm_bt<<<dim3(8, 4, B_), 256, 0, stream>>>(Wt,          0, Hn, sNC, Qb, sNC, 512,  512, 1.0f, bq, 1);
  gemm_bt<<<dim3(8, 4, B_), 256, 0, stream>>>(Wt + 262144, 0, Hn, sNC, Kb, sNC, 512,  512, 1.0f, bk, 1);
  // Vt[o][n]: A=Hn (rows n, M'=1024), B=Wv^T (rows o, N'=512), bias over cols(o)
  gemm_bt<<<dim3(4, 8, B_), 256, 0, stream>>>(Hn, sNC, Wt + 2 * 262144, 0, Vt, sNC, 512, 1024, 1.0f, bv, 2);
  // S[n][m]: A=K (rows m, M'=1024), B=Q (rows n, N'=1024), K-dim=512, scaled
  gemm_bt<<<dim3(8, 8, B_), 256, 0, stream>>>(Kb, sNC, Qb, sNC, P, sNN, 512, 1024, kScale, nullptr, 0);
  softmax_rows<<<B_ * N_, 256, 0, stream>>>(P);
  // H2[n][c]: A=Vt (rows c, M'=512), B=P (rows n, N'=1024), K-dim=1024
  gemm_bt<<<dim3(8, 4, B_), 256, 0, stream>>>(Vt, sNC, P, sNN, H2, sNC, 1024, 512, 1.0f, nullptr, 0);
  // out[o][n] = x + H2·Wn^T + bn
  gemm_bt_final<<<dim3(4, 8, B_), 256, 0, stream>>>(H2, Wt + 3 * 262144, x, bn, out, 512);
}

// Round 3
// 293.249 us; speedup vs baseline: 1.3567x; 1.1706x over previous
//
#include <hip/hip_runtime.h>
#include <cstdint>

#define B_   32
#define C_   512
#define N_   1024
#define G_   32
#define CG_  16

typedef unsigned short u16;

static constexpr float kEps   = 1e-5f;
static constexpr float kScale = 0.04419417382415922f;  // 512^-0.5

using f32x4  = __attribute__((ext_vector_type(4))) float;
using short8 = __attribute__((ext_vector_type(8))) short;

__device__ __forceinline__ u16 f2bf(float f) {
  uint32_t u = __builtin_bit_cast(uint32_t, f);
  u += 0x7fffu + ((u >> 16) & 1u);   // RNE
  return (u16)(u >> 16);
}
__device__ __forceinline__ float bf2f(u16 h) {
  return __builtin_bit_cast(float, (uint32_t)h << 16);
}

// async global->LDS, 16B per lane. LDS dest is wave-uniform base (HW adds lane*16).
__device__ __forceinline__ void gload16(const void* g, void* lds) {
  __builtin_amdgcn_global_load_lds(
      (__attribute__((address_space(1))) void*)(uintptr_t)g,
      (__attribute__((address_space(3))) void*)(uint32_t)(uintptr_t)lds,
      16, 0, 0);
}

// bijective XCD-chunked remap (m204): contiguous logical chunk per XCD.
__device__ __forceinline__ uint3 remap_xcd() {
  const int gx = gridDim.x, gy = gridDim.y, gz = gridDim.z;
  const int nwg = gx * gy * gz;
  const int lin = blockIdx.x + gx * (blockIdx.y + gy * blockIdx.z);
  const int q = nwg >> 3, r = nwg & 7;
  const int xcd = lin & 7, pos = lin >> 3;
  int nid = (xcd < r ? xcd * (q + 1) : r * (q + 1) + (xcd - r) * q) + pos;
  uint3 o;
  o.x = nid % gx; nid /= gx;
  o.y = nid % gy; o.z = nid / gy;
  return o;
}

// ---------------- weights: Wt[m][o][c] = bf16(W[c][o]), LDS tile transpose ----------------
__global__ __launch_bounds__(256) void wt_kernel(
    const float* __restrict__ Wq, const float* __restrict__ Wk,
    const float* __restrict__ Wv, const float* __restrict__ Wn,
    u16* __restrict__ Wt) {
  __shared__ float tile[64][65];
  const int m = blockIdx.z;
  const int c0 = blockIdx.y * 64, o0 = blockIdx.x * 64;
  const float* W = (m == 0) ? Wq : (m == 1) ? Wk : (m == 2) ? Wv : Wn;
  const int tx = threadIdx.x & 15, ty = threadIdx.x >> 4;
#pragma unroll
  for (int rr = 0; rr < 64; rr += 16) {
    const int c = c0 + ty + rr;
    const float4 v = *(const float4*)(W + (size_t)c * 512 + o0 + tx * 4);
    tile[ty + rr][tx * 4 + 0] = v.x;
    tile[ty + rr][tx * 4 + 1] = v.y;
    tile[ty + rr][tx * 4 + 2] = v.z;
    tile[ty + rr][tx * 4 + 3] = v.w;
  }
  __syncthreads();
#pragma unroll
  for (int rr = 0; rr < 64; rr += 16) {
    const int o = o0 + ty + rr;
    ushort4 st;
    st.x = f2bf(tile[tx * 4 + 0][ty + rr]);
    st.y = f2bf(tile[tx * 4 + 1][ty + rr]);
    st.z = f2bf(tile[tx * 4 + 2][ty + rr]);
    st.w = f2bf(tile[tx * 4 + 3][ty + rr]);
    *(ushort4*)(Wt + (size_t)m * 262144 + (size_t)o * 512 + c0 + tx * 4) = st;
  }
}

// ---------------- fused groupnorm: one pass over x, stats + normalize + transpose ------
// One block per (b,g): stage 16x1024 f32 in LDS (pad 1028), reduce, write Hn[b][n][c] bf16.
__global__ __launch_bounds__(256) void gn_fused(const float* __restrict__ x,
                                                u16* __restrict__ Hn) {
  __shared__ float lds[16 * 1028];
  __shared__ float red[10];
  const int bg = blockIdx.x, b = bg >> 5, g = bg & 31;
  const int t = threadIdx.x;
  const float4* p4 = (const float4*)(x + (size_t)bg * 16384);
  float s = 0.f, s2 = 0.f;
  for (int i = t; i < 4096; i += 256) {
    const float4 v = p4[i];
    const int e = i * 4, ic = e >> 10, n = e & 1023;
    *(float4*)(lds + ic * 1028 + n) = v;
    s  += v.x + v.y + v.z + v.w;
    s2 += v.x * v.x + v.y * v.y + v.z * v.z + v.w * v.w;
  }
#pragma unroll
  for (int o = 32; o; o >>= 1) { s += __shfl_xor(s, o); s2 += __shfl_xor(s2, o); }
  const int lane = t & 63, w = t >> 6;
  if (lane == 0) { red[w] = s; red[4 + w] = s2; }
  __syncthreads();
  if (t == 0) {
    s  = red[0] + red[1] + red[2] + red[3];
    s2 = red[4] + red[5] + red[6] + red[7];
    const float inv = 1.0f / 16384.0f;
    const float mean = s * inv;
    const float var  = s2 * inv - mean * mean;
    red[8] = mean;
    red[9] = rsqrtf(var + kEps);
  }
  __syncthreads();
  const float mean = red[8], rstd = red[9];
#pragma unroll
  for (int r = 0; r < 4; ++r) {
    const int n = t + 256 * r;
    ushort o8[16];
#pragma unroll
    for (int ic = 0; ic < 16; ++ic)
      o8[ic] = f2bf((lds[ic * 1028 + n] - mean) * rstd);
    u16* dst = Hn + ((size_t)(b * N_ + n)) * C_ + g * 16;
#pragma unroll
    for (int q = 0; q < 4; ++q) {
      ushort4 st; st.x = o8[q*4]; st.y = o8[q*4+1]; st.z = o8[q*4+2]; st.w = o8[q*4+3];
      *(ushort4*)(dst + q * 4) = st;
    }
  }
}

// ---------------- GEMM core v3: 256x256 tile, BK=64, 8 waves (2Mx4N), double-buffered LDS,
// counted vmcnt + raw s_barrier (T3-lite/T4), setprio around MFMA (T5), XOR-swizzle (T2).
// D[m][n] = sum_k A[m][k]*B[n][k], both row-major with ld=Ktot.
__device__ __forceinline__ void gemm_core256(
    const u16* __restrict__ A, const u16* __restrict__ B,
    int Ktot, int m0, int n0,
    u16* Alds, u16* Blds, f32x4 acc[8][4]) {
  const int tid = threadIdx.x, lane = tid & 63, wid = tid >> 6;
  const int wm = wid >> 2, wn = wid & 3;

  // staging: wave wid stages rows wid*32 .. +31 of both tiles (4 gloads x 8 rows each)
  const int sr  = lane >> 3;
  const int scb = (lane & 7) ^ sr;             // pre-swizzled source 16B-block
  const u16* Ag = A + (size_t)(m0 + wid * 32 + sr) * Ktot + scb * 8;
  const u16* Bg = B + (size_t)(n0 + wid * 32 + sr) * Ktot + scb * 8;
  char* Al = (char*)Alds + wid * 4096;
  char* Bl = (char*)Blds + wid * 4096;
  const long long r8 = (long long)8 * Ktot;    // 8 rows in elements

  const int arow = lane & 15, g4 = lane >> 4, rx = lane & 7;
  const int nt = Ktot >> 6;

#define STAGE_(d, koff)                                                        \
  {                                                                            \
    _Pragma("unroll")                                                          \
    for (int g_ = 0; g_ < 4; ++g_) {                                           \
      gload16(Ag + (koff) + g_ * r8, Al + (d) * 32768 + g_ * 1024);            \
      gload16(Bg + (koff) + g_ * r8, Bl + (d) * 32768 + g_ * 1024);            \
    }                                                                          \
  }

  STAGE_(0, 0);
  for (int t = 0; t < nt; ++t) {
    const int cur = t & 1;
    __builtin_amdgcn_sched_barrier(0);
    __builtin_amdgcn_s_barrier();            // WAR: prior reads of buf[cur^1] done
    if (t + 1 < nt) {
      STAGE_(cur ^ 1, (long long)(t + 1) * 64);
      asm volatile("s_waitcnt vmcnt(8)" ::: "memory");   // my 8 loads of buf[cur] landed
    } else {
      asm volatile("s_waitcnt vmcnt(0)" ::: "memory");
    }
    __builtin_amdgcn_s_barrier();            // RAW: buf[cur] complete for all waves
    __builtin_amdgcn_sched_barrier(0);
    const char* Ab = (const char*)Alds + cur * 32768;
    const char* Bb = (const char*)Blds + cur * 32768;
#pragma unroll
    for (int kk = 0; kk < 2; ++kk) {
      const int pc = ((kk * 4 + g4) ^ rx) * 16;          // swizzled phys byte col
      short8 a[8], b[4];
#pragma unroll
      for (int i = 0; i < 8; ++i)
        a[i] = *(const short8*)(Ab + (wm * 128 + i * 16 + arow) * 128 + pc);
#pragma unroll
      for (int j = 0; j < 4; ++j)
        b[j] = *(const short8*)(Bb + (wn * 64 + j * 16 + arow) * 128 + pc);
      __builtin_amdgcn_s_setprio(1);
#pragma unroll
      for (int i = 0; i < 8; ++i)
#pragma unroll
        for (int j = 0; j < 4; ++j)
          acc[i][j] = __builtin_amdgcn_mfma_f32_16x16x32_bf16(a[i], b[j], acc[i][j], 0, 0, 0);
      __builtin_amdgcn_s_setprio(0);
    }
  }
#undef STAGE_
}

// D fragment mapping (m89-verified): col = lane&15, row = (lane>>4)*4 + reg.
// Store at Out[col*LDC + row] -> per-lane 4 consecutive elements (ushort4).
__global__ __launch_bounds__(512, 2) void gemm_bt(
    const u16* __restrict__ A, long long sAz,
    const u16* __restrict__ B, long long sBz,
    u16* __restrict__ Out, long long sOz,
    int Ktot, int LDC, float scale,
    const float* __restrict__ bias, int biasMode) {
  __shared__ u16 Alds[2 * 256 * 64];
  __shared__ u16 Blds[2 * 256 * 64];
  const uint3 bid = remap_xcd();
  const int z = bid.z;
  A += (size_t)z * sAz;
  B += (size_t)z * sBz;
  u16* O = Out + (size_t)z * sOz;
  const int m0 = bid.y * 256, n0 = bid.x * 256;
  f32x4 acc[8][4] = {};
  gemm_core256(A, B, Ktot, m0, n0, Alds, Blds, acc);

  const int lane = threadIdx.x & 63, wid = threadIdx.x >> 6;
  const int wm = wid >> 2, wn = wid & 3;
#pragma unroll
  for (int i = 0; i < 8; ++i) {
    const int rowg = m0 + wm * 128 + i * 16 + ((lane >> 4) * 4);
    float b0 = 0.f, b1 = 0.f, b2 = 0.f, b3 = 0.f;
    if (biasMode == 1) {
      const float4 bv = *(const float4*)(bias + rowg);
      b0 = bv.x; b1 = bv.y; b2 = bv.z; b3 = bv.w;
    }
#pragma unroll
    for (int j = 0; j < 4; ++j) {
      const int colg = n0 + wn * 64 + j * 16 + (lane & 15);
      const float bc = (biasMode == 2) ? bias[colg] : 0.0f;
      const f32x4 v = acc[i][j];
      ushort4 st;
      st.x = f2bf(v[0] * scale + b0 + bc);
      st.y = f2bf(v[1] * scale + b1 + bc);
      st.z = f2bf(v[2] * scale + b2 + bc);
      st.w = f2bf(v[3] * scale + b3 + bc);
      *(ushort4*)(O + (size_t)colg * LDC + rowg) = st;
    }
  }
}

// final: D[n][o] = sum_c H2[n][c]*Wnt[o][c]; out[b][o][n] = x + D + bn[o]  (fp32)
__global__ __launch_bounds__(512, 2) void gemm_bt_final(
    const u16* __restrict__ A, const u16* __restrict__ Bw,
    const float* __restrict__ x, const float* __restrict__ bn,
    float* __restrict__ Out, int Ktot) {
  __shared__ u16 Alds[2 * 256 * 64];
  __shared__ u16 Blds[2 * 256 * 64];
  const uint3 bid = remap_xcd();
  const int z = bid.z;
  const u16*   Ab = A + (size_t)z * ((size_t)N_ * C_);
  const float* xb = x + (size_t)z * ((size_t)C_ * N_);
  float*       Ob = Out + (size_t)z * ((size_t)C_ * N_);
  const int m0 = bid.y * 256, n0 = bid.x * 256;
  f32x4 acc[8][4] = {};
  gemm_core256(Ab, Bw, Ktot, m0, n0, Alds, Blds, acc);

  const int lane = threadIdx.x & 63, wid = threadIdx.x >> 6;
  const int wm = wid >> 2, wn = wid & 3;
#pragma unroll
  for (int i = 0; i < 8; ++i) {
    const int rowg = m0 + wm * 128 + i * 16 + ((lane >> 4) * 4);   // n
#pragma unroll
    for (int j = 0; j < 4; ++j) {
      const int colg = n0 + wn * 64 + j * 16 + (lane & 15);        // o
      const float bc = bn[colg];
      const size_t off = (size_t)colg * N_ + rowg;
      const float4 xv = *(const float4*)(xb + off);
      const f32x4 v = acc[i][j];
      float4 ov;
      ov.x = xv.x + v[0] + bc;
      ov.y = xv.y + v[1] + bc;
      ov.z = xv.z + v[2] + bc;
      ov.w = xv.w + v[3] + bc;
      *(float4*)(Ob + off) = ov;
    }
  }
}

// ---------------- row softmax in-place on bf16 P[b*N+n][1024] ----------------
__global__ __launch_bounds__(256) void softmax_rows(u16* __restrict__ P) {
  __shared__ float red[8];
  u16* p = P + (size_t)blockIdx.x * 1024;
  const int tid = threadIdx.x;
  const ushort4 u = ((const ushort4*)p)[tid];
  const float v0 = bf2f(u.x), v1 = bf2f(u.y), v2 = bf2f(u.z), v3 = bf2f(u.w);
  float m = fmaxf(fmaxf(v0, v1), fmaxf(v2, v3));
#pragma unroll
  for (int o = 32; o; o >>= 1) m = fmaxf(m, __shfl_xor(m, o));
  const int lane = tid & 63, w = tid >> 6;
  if (lane == 0) red[w] = m;
  __syncthreads();
  m = fmaxf(fmaxf(red[0], red[1]), fmaxf(red[2], red[3]));
  const float e0 = __expf(v0 - m), e1 = __expf(v1 - m),
              e2 = __expf(v2 - m), e3 = __expf(v3 - m);
  float s = e0 + e1 + e2 + e3;
#pragma unroll
  for (int o = 32; o; o >>= 1) s += __shfl_xor(s, o);
  if (lane == 0) red[4 + w] = s;
  __syncthreads();
  s = red[4] + red[5] + red[6] + red[7];
  const float inv = 1.0f / s;
  ushort4 o4;
  o4.x = f2bf(e0 * inv); o4.y = f2bf(e1 * inv);
  o4.z = f2bf(e2 * inv); o4.w = f2bf(e3 * inv);
  ((ushort4*)p)[tid] = o4;
}

__global__ void sentinel_kernel(float* out, int n, float v) {
  const int i = blockIdx.x * blockDim.x + threadIdx.x;
  if (i < n) out[i] = v;
}

extern "C" void kernel_launch(void* const* d_in, const int* in_sizes, int n_in,
                              void* d_out, int out_size, void* d_ws, size_t ws_size,
                              hipStream_t stream) {
  const float* x  = (const float*)d_in[0];
  const float* Wq = (const float*)d_in[1];
  const float* bq = (const float*)d_in[2];
  const float* Wk = (const float*)d_in[3];
  const float* bk = (const float*)d_in[4];
  const float* Wv = (const float*)d_in[5];
  const float* bv = (const float*)d_in[6];
  const float* Wn = (const float*)d_in[7];
  const float* bn = (const float*)d_in[8];
  float* out = (float*)d_out;

  char* ws = (char*)d_ws;
  size_t off = 0;
  u16* Wt = (u16*)(ws + off);      off += (size_t)4 * 512 * 512 * 2;   // bf16 W^T x4
  const size_t bnc = (size_t)B_ * N_ * C_;
  u16* Hn = (u16*)(ws + off); off += bnc * 2;          // [b][n][c]
  u16* Qb = (u16*)(ws + off); off += bnc * 2;          // [b][n][c]
  u16* Kb = (u16*)(ws + off); off += bnc * 2;          // [b][m][c]
  u16* Vt = (u16*)(ws + off); off += bnc * 2;          // [b][c][m]
  u16* P  = (u16*)(ws + off); off += (size_t)B_ * N_ * N_ * 2;  // [b][n][m]
  u16* H2 = (u16*)(ws + off); off += bnc * 2;          // [b][n][c]

  if (ws_size < off) {
    const float v = 1.0e6f + (float)(ws_size >> 20);   // absmax ~ 1e6+MB -> diagnosable
    sentinel_kernel<<<(out_size + 255) / 256, 256, 0, stream>>>(out, out_size, v);
    return;
  }

  wt_kernel<<<dim3(8, 8, 4), 256, 0, stream>>>(Wq, Wk, Wv, Wn, Wt);
  gn_fused<<<B_ * G_, 256, 0, stream>>>(x, Hn);

  const long long sNC = (long long)N_ * C_;
  const long long sNN = (long long)N_ * N_;
  // Q[n][o]: A=Wq^T (rows o, M'=512), B=Hn (rows n, N'=1024), bias over rows(o)
  gemm_bt<<<dim3(4, 2, B_), 512, 0, stream>>>(Wt,          0, Hn, sNC, Qb, sNC, 512,  512, 1.0f, bq, 1);
  gemm_bt<<<dim3(4, 2, B_), 512, 0, stream>>>(Wt + 262144, 0, Hn, sNC, Kb, sNC, 512,  512, 1.0f, bk, 1);
  // Vt[o][n]: A=Hn (rows n, M'=1024), B=Wv^T (rows o, N'=512), bias over cols(o)
  gemm_bt<<<dim3(2, 4, B_), 512, 0, stream>>>(Hn, sNC, Wt + 2 * 262144, 0, Vt, sNC, 512, 1024, 1.0f, bv, 2);
  // S[n][m]: A=K (rows m, M'=1024), B=Q (rows n, N'=1024), K-dim=512, scaled
  gemm_bt<<<dim3(4, 4, B_), 512, 0, stream>>>(Kb, sNC, Qb, sNC, P, sNN, 512, 1024, kScale, nullptr, 0);
  softmax_rows<<<B_ * N_, 256, 0, stream>>>(P);
  // H2[n][c]: A=Vt (rows c, M'=512), B=P (rows n, N'=1024), K-dim=1024
  gemm_bt<<<dim3(4, 2, B_), 512, 0, stream>>>(Vt, sNC, P, sNN, H2, sNC, 1024, 512, 1.0f, nullptr, 0);
  // out[o][n] = x + H2·Wn^T + bn
  gemm_bt_final<<<dim3(2, 4, B_), 512, 0, stream>>>(H2, Wt + 3 * 262144, x, bn, out, 512);
}

// Round 4
// 290.659 us; speedup vs baseline: 1.3688x; 1.0089x over previous
//
#include <hip/hip_runtime.h>
#include <cstdint>

#define B_   32
#define C_   512
#define N_   1024
#define G_   32
#define CG_  16

typedef unsigned short u16;

static constexpr float kEps   = 1e-5f;
static constexpr float kScale = 0.04419417382415922f;  // 512^-0.5

using f32x4  = __attribute__((ext_vector_type(4))) float;
using short8 = __attribute__((ext_vector_type(8))) short;

__device__ __forceinline__ u16 f2bf(float f) {
  uint32_t u = __builtin_bit_cast(uint32_t, f);
  u += 0x7fffu + ((u >> 16) & 1u);   // RNE
  return (u16)(u >> 16);
}
__device__ __forceinline__ float bf2f(u16 h) {
  return __builtin_bit_cast(float, (uint32_t)h << 16);
}

// async global->LDS, 16B per lane. LDS dest is wave-uniform base (HW adds lane*16).
__device__ __forceinline__ void gload16(const void* g, void* lds) {
  __builtin_amdgcn_global_load_lds(
      (__attribute__((address_space(1))) void*)(uintptr_t)g,
      (__attribute__((address_space(3))) void*)(uint32_t)(uintptr_t)lds,
      16, 0, 0);
}

// bijective XCD-chunked remap (m204): contiguous logical chunk per XCD.
__device__ __forceinline__ uint3 remap_xcd() {
  const int gx = gridDim.x, gy = gridDim.y, gz = gridDim.z;
  const int nwg = gx * gy * gz;
  const int lin = blockIdx.x + gx * (blockIdx.y + gy * blockIdx.z);
  const int q = nwg >> 3, r = nwg & 7;
  const int xcd = lin & 7, pos = lin >> 3;
  int nid = (xcd < r ? xcd * (q + 1) : r * (q + 1) + (xcd - r) * q) + pos;
  uint3 o;
  o.x = nid % gx; nid /= gx;
  o.y = nid % gy; o.z = nid / gy;
  return o;
}

// ---------------- weights: Wt[m][o][c] = bf16(W[c][o]), LDS tile transpose ----------------
__global__ __launch_bounds__(256) void wt_kernel(
    const float* __restrict__ Wq, const float* __restrict__ Wk,
    const float* __restrict__ Wv, const float* __restrict__ Wn,
    u16* __restrict__ Wt) {
  __shared__ float tile[64][65];
  const int m = blockIdx.z;
  const int c0 = blockIdx.y * 64, o0 = blockIdx.x * 64;
  const float* W = (m == 0) ? Wq : (m == 1) ? Wk : (m == 2) ? Wv : Wn;
  const int tx = threadIdx.x & 15, ty = threadIdx.x >> 4;
#pragma unroll
  for (int rr = 0; rr < 64; rr += 16) {
    const int c = c0 + ty + rr;
    const float4 v = *(const float4*)(W + (size_t)c * 512 + o0 + tx * 4);
    tile[ty + rr][tx * 4 + 0] = v.x;
    tile[ty + rr][tx * 4 + 1] = v.y;
    tile[ty + rr][tx * 4 + 2] = v.z;
    tile[ty + rr][tx * 4 + 3] = v.w;
  }
  __syncthreads();
#pragma unroll
  for (int rr = 0; rr < 64; rr += 16) {
    const int o = o0 + ty + rr;
    ushort4 st;
    st.x = f2bf(tile[tx * 4 + 0][ty + rr]);
    st.y = f2bf(tile[tx * 4 + 1][ty + rr]);
    st.z = f2bf(tile[tx * 4 + 2][ty + rr]);
    st.w = f2bf(tile[tx * 4 + 3][ty + rr]);
    *(ushort4*)(Wt + (size_t)m * 262144 + (size_t)o * 512 + c0 + tx * 4) = st;
  }
}

// ---------------- fused groupnorm: one pass over x, stats + normalize + transpose ------
__global__ __launch_bounds__(256) void gn_fused(const float* __restrict__ x,
                                                u16* __restrict__ Hn) {
  __shared__ float lds[16 * 1028];
  __shared__ float red[10];
  const int bg = blockIdx.x, b = bg >> 5, g = bg & 31;
  const int t = threadIdx.x;
  const float4* p4 = (const float4*)(x + (size_t)bg * 16384);
  float s = 0.f, s2 = 0.f;
  for (int i = t; i < 4096; i += 256) {
    const float4 v = p4[i];
    const int e = i * 4, ic = e >> 10, n = e & 1023;
    *(float4*)(lds + ic * 1028 + n) = v;
    s  += v.x + v.y + v.z + v.w;
    s2 += v.x * v.x + v.y * v.y + v.z * v.z + v.w * v.w;
  }
#pragma unroll
  for (int o = 32; o; o >>= 1) { s += __shfl_xor(s, o); s2 += __shfl_xor(s2, o); }
  const int lane = t & 63, w = t >> 6;
  if (lane == 0) { red[w] = s; red[4 + w] = s2; }
  __syncthreads();
  if (t == 0) {
    s  = red[0] + red[1] + red[2] + red[3];
    s2 = red[4] + red[5] + red[6] + red[7];
    const float inv = 1.0f / 16384.0f;
    const float mean = s * inv;
    const float var  = s2 * inv - mean * mean;
    red[8] = mean;
    red[9] = rsqrtf(var + kEps);
  }
  __syncthreads();
  const float mean = red[8], rstd = red[9];
#pragma unroll
  for (int r = 0; r < 4; ++r) {
    const int n = t + 256 * r;
    ushort o8[16];
#pragma unroll
    for (int ic = 0; ic < 16; ++ic)
      o8[ic] = f2bf((lds[ic * 1028 + n] - mean) * rstd);
    u16* dst = Hn + ((size_t)(b * N_ + n)) * C_ + g * 16;
#pragma unroll
    for (int q = 0; q < 4; ++q) {
      ushort4 st; st.x = o8[q*4]; st.y = o8[q*4+1]; st.z = o8[q*4+2]; st.w = o8[q*4+3];
      *(ushort4*)(dst + q * 4) = st;
    }
  }
}

// ---------------- GEMM core v4: 256x256 tile, BK=64, 8 waves (2Mx4N), double-buffered LDS,
// 8-PHASE schedule (T3+T4): 4 phases per K-tile, each {ds_read subtile | stage-issue |
// s_barrier | setprio(1) 16 MFMA setprio(0) | s_barrier}; all next-tile stages issued in
// phases 0-1 so the once-per-tile boundary vmcnt(0) only waits on >=2-phase-old loads.
// XOR-swizzle (T2) on both sides (pre-swizzled global source + swizzled ds_read).
__device__ __forceinline__ void gemm_core256(
    const u16* __restrict__ A, const u16* __restrict__ B,
    int Ktot, int m0, int n0,
    u16* Alds, u16* Blds, f32x4 acc0[4][4], f32x4 acc1[4][4]) {
  const int tid = threadIdx.x, lane = tid & 63, wid = tid >> 6;
  const int wm = wid >> 2, wn = wid & 3;

  // staging: wave wid stages rows wid*32 .. +31 of both tiles (4 gloads x 8 rows each)
  const int sr  = lane >> 3;
  const int scb = (lane & 7) ^ sr;             // pre-swizzled source 16B-block
  const u16* Ag = A + (size_t)(m0 + wid * 32 + sr) * Ktot + scb * 8;
  const u16* Bg = B + (size_t)(n0 + wid * 32 + sr) * Ktot + scb * 8;
  char* Al = (char*)Alds + wid * 4096;
  char* Bl = (char*)Blds + wid * 4096;
  const long long r8 = (long long)8 * Ktot;    // 8 rows in elements

  const int arow = lane & 15, g4 = lane >> 4, rx = lane & 7;
  const int nt = Ktot >> 6;

  // prologue: stage tile 0 into buf 0, drain once
#pragma unroll
  for (int g = 0; g < 4; ++g) {
    gload16(Ag + g * r8, Al + g * 1024);
    gload16(Bg + g * r8, Bl + g * 1024);
  }
  asm volatile("s_waitcnt vmcnt(0)" ::: "memory");
  __builtin_amdgcn_s_barrier();

  for (int t = 0; t < nt; ++t) {
    const int cur = t & 1;
    const char* Ab = (const char*)Alds + cur * 32768;
    const char* Bb = (const char*)Blds + cur * 32768;
    char* Aln = Al + (cur ^ 1) * 32768;
    char* Bln = Bl + (cur ^ 1) * 32768;
    const bool nx = (t + 1 < nt);
    const long long ko = (long long)(t + 1) * 64;
    const int pc0 = (g4 ^ rx) * 16;            // kk0 swizzled phys byte col
    const int pc1 = ((4 + g4) ^ rx) * 16;      // kk1
    short8 a[4], b[4];

    // ---------- phase 0: kk0 x mh0 ; stage next B (4 gloads) ----------
#pragma unroll
    for (int i = 0; i < 4; ++i)
      a[i] = *(const short8*)(Ab + (wm * 128 + i * 16 + arow) * 128 + pc0);
#pragma unroll
    for (int j = 0; j < 4; ++j)
      b[j] = *(const short8*)(Bb + (wn * 64 + j * 16 + arow) * 128 + pc0);
    if (nx) {
#pragma unroll
      for (int g = 0; g < 4; ++g) gload16(Bg + ko + g * r8, Bln + g * 1024);
    }
    __builtin_amdgcn_s_barrier();
    __builtin_amdgcn_sched_barrier(0);
    __builtin_amdgcn_s_setprio(1);
#pragma unroll
    for (int i = 0; i < 4; ++i)
#pragma unroll
      for (int j = 0; j < 4; ++j)
        acc0[i][j] = __builtin_amdgcn_mfma_f32_16x16x32_bf16(a[i], b[j], acc0[i][j], 0, 0, 0);
    __builtin_amdgcn_s_setprio(0);
    __builtin_amdgcn_sched_barrier(0);
    __builtin_amdgcn_s_barrier();

    // ---------- phase 1: kk0 x mh1 ; stage next A (4 gloads) ----------
#pragma unroll
    for (int i = 0; i < 4; ++i)
      a[i] = *(const short8*)(Ab + (wm * 128 + (i + 4) * 16 + arow) * 128 + pc0);
    if (nx) {
#pragma unroll
      for (int g = 0; g < 4; ++g) gload16(Ag + ko + g * r8, Aln + g * 1024);
    }
    __builtin_amdgcn_s_barrier();
    __builtin_amdgcn_sched_barrier(0);
    __builtin_amdgcn_s_setprio(1);
#pragma unroll
    for (int i = 0; i < 4; ++i)
#pragma unroll
      for (int j = 0; j < 4; ++j)
        acc1[i][j] = __builtin_amdgcn_mfma_f32_16x16x32_bf16(a[i], b[j], acc1[i][j], 0, 0, 0);
    __builtin_amdgcn_s_setprio(0);
    __builtin_amdgcn_sched_barrier(0);
    __builtin_amdgcn_s_barrier();

    // ---------- phase 2: kk1 x mh0 ----------
#pragma unroll
    for (int i = 0; i < 4; ++i)
      a[i] = *(const short8*)(Ab + (wm * 128 + i * 16 + arow) * 128 + pc1);
#pragma unroll
    for (int j = 0; j < 4; ++j)
      b[j] = *(const short8*)(Bb + (wn * 64 + j * 16 + arow) * 128 + pc1);
    __builtin_amdgcn_s_barrier();
    __builtin_amdgcn_sched_barrier(0);
    __builtin_amdgcn_s_setprio(1);
#pragma unroll
    for (int i = 0; i < 4; ++i)
#pragma unroll
      for (int j = 0; j < 4; ++j)
        acc0[i][j] = __builtin_amdgcn_mfma_f32_16x16x32_bf16(a[i], b[j], acc0[i][j], 0, 0, 0);
    __builtin_amdgcn_s_setprio(0);
    __builtin_amdgcn_sched_barrier(0);
    __builtin_amdgcn_s_barrier();

    // ---------- phase 3: kk1 x mh1 ; tile boundary ----------
#pragma unroll
    for (int i = 0; i < 4; ++i)
      a[i] = *(const short8*)(Ab + (wm * 128 + (i + 4) * 16 + arow) * 128 + pc1);
    __builtin_amdgcn_s_barrier();
    __builtin_amdgcn_sched_barrier(0);
    __builtin_amdgcn_s_setprio(1);
#pragma unroll
    for (int i = 0; i < 4; ++i)
#pragma unroll
      for (int j = 0; j < 4; ++j)
        acc1[i][j] = __builtin_amdgcn_mfma_f32_16x16x32_bf16(a[i], b[j], acc1[i][j], 0, 0, 0);
    __builtin_amdgcn_s_setprio(0);
    __builtin_amdgcn_sched_barrier(0);
    // boundary: next tile's 8 loads were issued in phases 0-1 (>=2 phases ago);
    // nothing younger is outstanding, so vmcnt(0) == counted wait, no recent-drain.
    asm volatile("s_waitcnt vmcnt(0)" ::: "memory");
    __builtin_amdgcn_s_barrier();
  }
}

// D fragment mapping (m89-verified): col = lane&15, row = (lane>>4)*4 + reg.
// Store at Out[col*LDC + row] -> per-lane 4 consecutive elements (ushort4).
__global__ __launch_bounds__(512, 2) void gemm_bt(
    const u16* __restrict__ A, long long sAz,
    const u16* __restrict__ B, long long sBz,
    u16* __restrict__ Out, long long sOz,
    int Ktot, int LDC, float scale,
    const float* __restrict__ bias, int biasMode) {
  __shared__ u16 Alds[2 * 256 * 64];
  __shared__ u16 Blds[2 * 256 * 64];
  const uint3 bid = remap_xcd();
  const int z = bid.z;
  A += (size_t)z * sAz;
  B += (size_t)z * sBz;
  u16* O = Out + (size_t)z * sOz;
  const int m0 = bid.y * 256, n0 = bid.x * 256;
  f32x4 acc0[4][4] = {};
  f32x4 acc1[4][4] = {};
  gemm_core256(A, B, Ktot, m0, n0, Alds, Blds, acc0, acc1);

  const int lane = threadIdx.x & 63, wid = threadIdx.x >> 6;
  const int wm = wid >> 2, wn = wid & 3;
#pragma unroll
  for (int i = 0; i < 8; ++i) {
    const int rowg = m0 + wm * 128 + i * 16 + ((lane >> 4) * 4);
    float b0 = 0.f, b1 = 0.f, b2 = 0.f, b3 = 0.f;
    if (biasMode == 1) {
      const float4 bv = *(const float4*)(bias + rowg);
      b0 = bv.x; b1 = bv.y; b2 = bv.z; b3 = bv.w;
    }
#pragma unroll
    for (int j = 0; j < 4; ++j) {
      const int colg = n0 + wn * 64 + j * 16 + (lane & 15);
      const float bc = (biasMode == 2) ? bias[colg] : 0.0f;
      const f32x4 v = (i < 4) ? acc0[i][j] : acc1[i - 4][j];
      ushort4 st;
      st.x = f2bf(v[0] * scale + b0 + bc);
      st.y = f2bf(v[1] * scale + b1 + bc);
      st.z = f2bf(v[2] * scale + b2 + bc);
      st.w = f2bf(v[3] * scale + b3 + bc);
      *(ushort4*)(O + (size_t)colg * LDC + rowg) = st;
    }
  }
}

// final: D[n][o] = sum_c H2[n][c]*Wnt[o][c]; out[b][o][n] = x + D + bn[o]  (fp32)
__global__ __launch_bounds__(512, 2) void gemm_bt_final(
    const u16* __restrict__ A, const u16* __restrict__ Bw,
    const float* __restrict__ x, const float* __restrict__ bn,
    float* __restrict__ Out, int Ktot) {
  __shared__ u16 Alds[2 * 256 * 64];
  __shared__ u16 Blds[2 * 256 * 64];
  const uint3 bid = remap_xcd();
  const int z = bid.z;
  const u16*   Ab = A + (size_t)z * ((size_t)N_ * C_);
  const float* xb = x + (size_t)z * ((size_t)C_ * N_);
  float*       Ob = Out + (size_t)z * ((size_t)C_ * N_);
  const int m0 = bid.y * 256, n0 = bid.x * 256;
  f32x4 acc0[4][4] = {};
  f32x4 acc1[4][4] = {};
  gemm_core256(Ab, Bw, Ktot, m0, n0, Alds, Blds, acc0, acc1);

  const int lane = threadIdx.x & 63, wid = threadIdx.x >> 6;
  const int wm = wid >> 2, wn = wid & 3;
#pragma unroll
  for (int i = 0; i < 8; ++i) {
    const int rowg = m0 + wm * 128 + i * 16 + ((lane >> 4) * 4);   // n
#pragma unroll
    for (int j = 0; j < 4; ++j) {
      const int colg = n0 + wn * 64 + j * 16 + (lane & 15);        // o
      const float bc = bn[colg];
      const size_t off = (size_t)colg * N_ + rowg;
      const float4 xv = *(const float4*)(xb + off);
      const f32x4 v = (i < 4) ? acc0[i][j] : acc1[i - 4][j];
      float4 ov;
      ov.x = xv.x + v[0] + bc;
      ov.y = xv.y + v[1] + bc;
      ov.z = xv.z + v[2] + bc;
      ov.w = xv.w + v[3] + bc;
      *(float4*)(Ob + off) = ov;
    }
  }
}

// ---------------- row softmax in-place on bf16 P[b*N+n][1024] ----------------
__global__ __launch_bounds__(256) void softmax_rows(u16* __restrict__ P) {
  __shared__ float red[8];
  u16* p = P + (size_t)blockIdx.x * 1024;
  const int tid = threadIdx.x;
  const ushort4 u = ((const ushort4*)p)[tid];
  const float v0 = bf2f(u.x), v1 = bf2f(u.y), v2 = bf2f(u.z), v3 = bf2f(u.w);
  float m = fmaxf(fmaxf(v0, v1), fmaxf(v2, v3));
#pragma unroll
  for (int o = 32; o; o >>= 1) m = fmaxf(m, __shfl_xor(m, o));
  const int lane = tid & 63, w = tid >> 6;
  if (lane == 0) red[w] = m;
  __syncthreads();
  m = fmaxf(fmaxf(red[0], red[1]), fmaxf(red[2], red[3]));
  const float e0 = __expf(v0 - m), e1 = __expf(v1 - m),
              e2 = __expf(v2 - m), e3 = __expf(v3 - m);
  float s = e0 + e1 + e2 + e3;
#pragma unroll
  for (int o = 32; o; o >>= 1) s += __shfl_xor(s, o);
  if (lane == 0) red[4 + w] = s;
  __syncthreads();
  s = red[4] + red[5] + red[6] + red[7];
  const float inv = 1.0f / s;
  ushort4 o4;
  o4.x = f2bf(e0 * inv); o4.y = f2bf(e1 * inv);
  o4.z = f2bf(e2 * inv); o4.w = f2bf(e3 * inv);
  ((ushort4*)p)[tid] = o4;
}

__global__ void sentinel_kernel(float* out, int n, float v) {
  const int i = blockIdx.x * blockDim.x + threadIdx.x;
  if (i < n) out[i] = v;
}

extern "C" void kernel_launch(void* const* d_in, const int* in_sizes, int n_in,
                              void* d_out, int out_size, void* d_ws, size_t ws_size,
                              hipStream_t stream) {
  const float* x  = (const float*)d_in[0];
  const float* Wq = (const float*)d_in[1];
  const float* bq = (const float*)d_in[2];
  const float* Wk = (const float*)d_in[3];
  const float* bk = (const float*)d_in[4];
  const float* Wv = (const float*)d_in[5];
  const float* bv = (const float*)d_in[6];
  const float* Wn = (const float*)d_in[7];
  const float* bn = (const float*)d_in[8];
  float* out = (float*)d_out;

  char* ws = (char*)d_ws;
  size_t off = 0;
  u16* Wt = (u16*)(ws + off);      off += (size_t)4 * 512 * 512 * 2;   // bf16 W^T x4
  const size_t bnc = (size_t)B_ * N_ * C_;
  u16* Hn = (u16*)(ws + off); off += bnc * 2;          // [b][n][c]
  u16* Qb = (u16*)(ws + off); off += bnc * 2;          // [b][n][c]
  u16* Kb = (u16*)(ws + off); off += bnc * 2;          // [b][m][c]
  u16* Vt = (u16*)(ws + off); off += bnc * 2;          // [b][c][m]
  u16* P  = (u16*)(ws + off); off += (size_t)B_ * N_ * N_ * 2;  // [b][n][m]
  u16* H2 = (u16*)(ws + off); off += bnc * 2;          // [b][n][c]

  if (ws_size < off) {
    const float v = 1.0e6f + (float)(ws_size >> 20);   // absmax ~ 1e6+MB -> diagnosable
    sentinel_kernel<<<(out_size + 255) / 256, 256, 0, stream>>>(out, out_size, v);
    return;
  }

  wt_kernel<<<dim3(8, 8, 4), 256, 0, stream>>>(Wq, Wk, Wv, Wn, Wt);
  gn_fused<<<B_ * G_, 256, 0, stream>>>(x, Hn);

  const long long sNC = (long long)N_ * C_;
  const long long sNN = (long long)N_ * N_;
  // Q[n][o]: A=Wq^T (rows o, M'=512), B=Hn (rows n, N'=1024), bias over rows(o)
  gemm_bt<<<dim3(4, 2, B_), 512, 0, stream>>>(Wt,          0, Hn, sNC, Qb, sNC, 512,  512, 1.0f, bq, 1);
  gemm_bt<<<dim3(4, 2, B_), 512, 0, stream>>>(Wt + 262144, 0, Hn, sNC, Kb, sNC, 512,  512, 1.0f, bk, 1);
  // Vt[o][n]: A=Hn (rows n, M'=1024), B=Wv^T (rows o, N'=512), bias over cols(o)
  gemm_bt<<<dim3(2, 4, B_), 512, 0, stream>>>(Hn, sNC, Wt + 2 * 262144, 0, Vt, sNC, 512, 1024, 1.0f, bv, 2);
  // S[n][m]: A=K (rows m, M'=1024), B=Q (rows n, N'=1024), K-dim=512, scaled
  gemm_bt<<<dim3(4, 4, B_), 512, 0, stream>>>(Kb, sNC, Qb, sNC, P, sNN, 512, 1024, kScale, nullptr, 0);
  softmax_rows<<<B_ * N_, 256, 0, stream>>>(P);
  // H2[n][c]: A=Vt (rows c, M'=512), B=P (rows n, N'=1024), K-dim=1024
  gemm_bt<<<dim3(4, 2, B_), 512, 0, stream>>>(Vt, sNC, P, sNN, H2, sNC, 1024, 512, 1.0f, nullptr, 0);
  // out[o][n] = x + H2·Wn^T + bn
  gemm_bt_final<<<dim3(2, 4, B_), 512, 0, stream>>>(H2, Wt + 3 * 262144, x, bn, out, 512);
}

// Round 5
// 274.970 us; speedup vs baseline: 1.4469x; 1.0571x over previous
//
#include <hip/hip_runtime.h>
#include <cstdint>

#define B_   32
#define C_   512
#define N_   1024
#define G_   32
#define CG_  16

typedef unsigned short u16;

static constexpr float kEps   = 1e-5f;
static constexpr float kScale = 0.04419417382415922f;  // 512^-0.5

using f32x4  = __attribute__((ext_vector_type(4))) float;
using short8 = __attribute__((ext_vector_type(8))) short;

__device__ __forceinline__ u16 f2bf(float f) {
  uint32_t u = __builtin_bit_cast(uint32_t, f);
  u += 0x7fffu + ((u >> 16) & 1u);   // RNE
  return (u16)(u >> 16);
}
__device__ __forceinline__ float bf2f(u16 h) {
  return __builtin_bit_cast(float, (uint32_t)h << 16);
}

// async global->LDS, 16B per lane. LDS dest is wave-uniform base (HW adds lane*16).
__device__ __forceinline__ void gload16(const void* g, void* lds) {
  __builtin_amdgcn_global_load_lds(
      (__attribute__((address_space(1))) void*)(uintptr_t)g,
      (__attribute__((address_space(3))) void*)(uint32_t)(uintptr_t)lds,
      16, 0, 0);
}

// bijective XCD-chunked remap (m204): contiguous logical chunk per XCD.
__device__ __forceinline__ uint3 remap_xcd() {
  const int gx = gridDim.x, gy = gridDim.y, gz = gridDim.z;
  const int nwg = gx * gy * gz;
  const int lin = blockIdx.x + gx * (blockIdx.y + gy * blockIdx.z);
  const int q = nwg >> 3, r = nwg & 7;
  const int xcd = lin & 7, pos = lin >> 3;
  int nid = (xcd < r ? xcd * (q + 1) : r * (q + 1) + (xcd - r) * q) + pos;
  uint3 o;
  o.x = nid % gx; nid /= gx;
  o.y = nid % gy; o.z = nid / gy;
  return o;
}

// ---------------- weights: Wt[m][o][c] = bf16(W[c][o]), LDS tile transpose ----------------
__global__ __launch_bounds__(256) void wt_kernel(
    const float* __restrict__ Wq, const float* __restrict__ Wk,
    const float* __restrict__ Wv, const float* __restrict__ Wn,
    u16* __restrict__ Wt) {
  __shared__ float tile[64][65];
  const int m = blockIdx.z;
  const int c0 = blockIdx.y * 64, o0 = blockIdx.x * 64;
  const float* W = (m == 0) ? Wq : (m == 1) ? Wk : (m == 2) ? Wv : Wn;
  const int tx = threadIdx.x & 15, ty = threadIdx.x >> 4;
#pragma unroll
  for (int rr = 0; rr < 64; rr += 16) {
    const int c = c0 + ty + rr;
    const float4 v = *(const float4*)(W + (size_t)c * 512 + o0 + tx * 4);
    tile[ty + rr][tx * 4 + 0] = v.x;
    tile[ty + rr][tx * 4 + 1] = v.y;
    tile[ty + rr][tx * 4 + 2] = v.z;
    tile[ty + rr][tx * 4 + 3] = v.w;
  }
  __syncthreads();
#pragma unroll
  for (int rr = 0; rr < 64; rr += 16) {
    const int o = o0 + ty + rr;
    ushort4 st;
    st.x = f2bf(tile[tx * 4 + 0][ty + rr]);
    st.y = f2bf(tile[tx * 4 + 1][ty + rr]);
    st.z = f2bf(tile[tx * 4 + 2][ty + rr]);
    st.w = f2bf(tile[tx * 4 + 3][ty + rr]);
    *(ushort4*)(Wt + (size_t)m * 262144 + (size_t)o * 512 + c0 + tx * 4) = st;
  }
}

// ---------------- fused groupnorm: one pass over x, stats + normalize + transpose ------
__global__ __launch_bounds__(256) void gn_fused(const float* __restrict__ x,
                                                u16* __restrict__ Hn) {
  __shared__ float lds[16 * 1028];
  __shared__ float red[10];
  const int bg = blockIdx.x, b = bg >> 5, g = bg & 31;
  const int t = threadIdx.x;
  const float4* p4 = (const float4*)(x + (size_t)bg * 16384);
  float s = 0.f, s2 = 0.f;
  for (int i = t; i < 4096; i += 256) {
    const float4 v = p4[i];
    const int e = i * 4, ic = e >> 10, n = e & 1023;
    *(float4*)(lds + ic * 1028 + n) = v;
    s  += v.x + v.y + v.z + v.w;
    s2 += v.x * v.x + v.y * v.y + v.z * v.z + v.w * v.w;
  }
#pragma unroll
  for (int o = 32; o; o >>= 1) { s += __shfl_xor(s, o); s2 += __shfl_xor(s2, o); }
  const int lane = t & 63, w = t >> 6;
  if (lane == 0) { red[w] = s; red[4 + w] = s2; }
  __syncthreads();
  if (t == 0) {
    s  = red[0] + red[1] + red[2] + red[3];
    s2 = red[4] + red[5] + red[6] + red[7];
    const float inv = 1.0f / 16384.0f;
    const float mean = s * inv;
    const float var  = s2 * inv - mean * mean;
    red[8] = mean;
    red[9] = rsqrtf(var + kEps);
  }
  __syncthreads();
  const float mean = red[8], rstd = red[9];
#pragma unroll
  for (int r = 0; r < 4; ++r) {
    const int n = t + 256 * r;
    ushort o8[16];
#pragma unroll
    for (int ic = 0; ic < 16; ++ic)
      o8[ic] = f2bf((lds[ic * 1028 + n] - mean) * rstd);
    u16* dst = Hn + ((size_t)(b * N_ + n)) * C_ + g * 16;
#pragma unroll
    for (int q = 0; q < 4; ++q) {
      ushort4 st; st.x = o8[q*4]; st.y = o8[q*4+1]; st.z = o8[q*4+2]; st.w = o8[q*4+3];
      *(ushort4*)(dst + q * 4) = st;
    }
  }
}

// ---------------- GEMM core: 256x256 tile, BK=64, 8 waves (2Mx4N), double-buffered LDS,
// 8-phase schedule; all next-tile stages issued in phases 0-1; boundary vmcnt(0) only
// waits on >=2-phase-old loads. XOR-swizzle on both sides.
__device__ __forceinline__ void gemm_core256(
    const u16* __restrict__ A, const u16* __restrict__ B,
    int Ktot, int m0, int n0,
    u16* Alds, u16* Blds, f32x4 acc0[4][4], f32x4 acc1[4][4]) {
  const int tid = threadIdx.x, lane = tid & 63, wid = tid >> 6;
  const int wm = wid >> 2, wn = wid & 3;

  const int sr  = lane >> 3;
  const int scb = (lane & 7) ^ sr;             // pre-swizzled source 16B-block
  const u16* Ag = A + (size_t)(m0 + wid * 32 + sr) * Ktot + scb * 8;
  const u16* Bg = B + (size_t)(n0 + wid * 32 + sr) * Ktot + scb * 8;
  char* Al = (char*)Alds + wid * 4096;
  char* Bl = (char*)Blds + wid * 4096;
  const long long r8 = (long long)8 * Ktot;    // 8 rows in elements

  const int arow = lane & 15, g4 = lane >> 4, rx = lane & 7;
  const int nt = Ktot >> 6;

  // prologue: stage tile 0 into buf 0, drain once
#pragma unroll
  for (int g = 0; g < 4; ++g) {
    gload16(Ag + g * r8, Al + g * 1024);
    gload16(Bg + g * r8, Bl + g * 1024);
  }
  asm volatile("s_waitcnt vmcnt(0)" ::: "memory");
  __builtin_amdgcn_s_barrier();

  for (int t = 0; t < nt; ++t) {
    const int cur = t & 1;
    const char* Ab = (const char*)Alds + cur * 32768;
    const char* Bb = (const char*)Blds + cur * 32768;
    char* Aln = Al + (cur ^ 1) * 32768;
    char* Bln = Bl + (cur ^ 1) * 32768;
    const bool nx = (t + 1 < nt);
    const long long ko = (long long)(t + 1) * 64;
    const int pc0 = (g4 ^ rx) * 16;            // kk0 swizzled phys byte col
    const int pc1 = ((4 + g4) ^ rx) * 16;      // kk1
    short8 a[4], b[4];

    // ---------- phase 0: kk0 x mh0 ; stage next B ----------
#pragma unroll
    for (int i = 0; i < 4; ++i)
      a[i] = *(const short8*)(Ab + (wm * 128 + i * 16 + arow) * 128 + pc0);
#pragma unroll
    for (int j = 0; j < 4; ++j)
      b[j] = *(const short8*)(Bb + (wn * 64 + j * 16 + arow) * 128 + pc0);
    if (nx) {
#pragma unroll
      for (int g = 0; g < 4; ++g) gload16(Bg + ko + g * r8, Bln + g * 1024);
    }
    __builtin_amdgcn_s_barrier();
    __builtin_amdgcn_sched_barrier(0);
    __builtin_amdgcn_s_setprio(1);
#pragma unroll
    for (int i = 0; i < 4; ++i)
#pragma unroll
      for (int j = 0; j < 4; ++j)
        acc0[i][j] = __builtin_amdgcn_mfma_f32_16x16x32_bf16(a[i], b[j], acc0[i][j], 0, 0, 0);
    __builtin_amdgcn_s_setprio(0);
    __builtin_amdgcn_sched_barrier(0);
    __builtin_amdgcn_s_barrier();

    // ---------- phase 1: kk0 x mh1 ; stage next A ----------
#pragma unroll
    for (int i = 0; i < 4; ++i)
      a[i] = *(const short8*)(Ab + (wm * 128 + (i + 4) * 16 + arow) * 128 + pc0);
    if (nx) {
#pragma unroll
      for (int g = 0; g < 4; ++g) gload16(Ag + ko + g * r8, Aln + g * 1024);
    }
    __builtin_amdgcn_s_barrier();
    __builtin_amdgcn_sched_barrier(0);
    __builtin_amdgcn_s_setprio(1);
#pragma unroll
    for (int i = 0; i < 4; ++i)
#pragma unroll
      for (int j = 0; j < 4; ++j)
        acc1[i][j] = __builtin_amdgcn_mfma_f32_16x16x32_bf16(a[i], b[j], acc1[i][j], 0, 0, 0);
    __builtin_amdgcn_s_setprio(0);
    __builtin_amdgcn_sched_barrier(0);
    __builtin_amdgcn_s_barrier();

    // ---------- phase 2: kk1 x mh0 ----------
#pragma unroll
    for (int i = 0; i < 4; ++i)
      a[i] = *(const short8*)(Ab + (wm * 128 + i * 16 + arow) * 128 + pc1);
#pragma unroll
    for (int j = 0; j < 4; ++j)
      b[j] = *(const short8*)(Bb + (wn * 64 + j * 16 + arow) * 128 + pc1);
    __builtin_amdgcn_s_barrier();
    __builtin_amdgcn_sched_barrier(0);
    __builtin_amdgcn_s_setprio(1);
#pragma unroll
    for (int i = 0; i < 4; ++i)
#pragma unroll
      for (int j = 0; j < 4; ++j)
        acc0[i][j] = __builtin_amdgcn_mfma_f32_16x16x32_bf16(a[i], b[j], acc0[i][j], 0, 0, 0);
    __builtin_amdgcn_s_setprio(0);
    __builtin_amdgcn_sched_barrier(0);
    __builtin_amdgcn_s_barrier();

    // ---------- phase 3: kk1 x mh1 ; tile boundary ----------
#pragma unroll
    for (int i = 0; i < 4; ++i)
      a[i] = *(const short8*)(Ab + (wm * 128 + (i + 4) * 16 + arow) * 128 + pc1);
    __builtin_amdgcn_s_barrier();
    __builtin_amdgcn_sched_barrier(0);
    __builtin_amdgcn_s_setprio(1);
#pragma unroll
    for (int i = 0; i < 4; ++i)
#pragma unroll
      for (int j = 0; j < 4; ++j)
        acc1[i][j] = __builtin_amdgcn_mfma_f32_16x16x32_bf16(a[i], b[j], acc1[i][j], 0, 0, 0);
    __builtin_amdgcn_s_setprio(0);
    __builtin_amdgcn_sched_barrier(0);
    asm volatile("s_waitcnt vmcnt(0)" ::: "memory");
    __builtin_amdgcn_s_barrier();
  }
}

// D fragment mapping (m89-verified): col = lane&15, row = (lane>>4)*4 + reg.
__global__ __launch_bounds__(512, 2) void gemm_bt(
    const u16* __restrict__ A, long long sAz,
    const u16* __restrict__ B, long long sBz,
    u16* __restrict__ Out, long long sOz,
    int Ktot, int LDC, float scale,
    const float* __restrict__ bias, int biasMode) {
  __shared__ u16 Alds[2 * 256 * 64];
  __shared__ u16 Blds[2 * 256 * 64];
  const uint3 bid = remap_xcd();
  const int z = bid.z;
  A += (size_t)z * sAz;
  B += (size_t)z * sBz;
  u16* O = Out + (size_t)z * sOz;
  const int m0 = bid.y * 256, n0 = bid.x * 256;
  f32x4 acc0[4][4] = {};
  f32x4 acc1[4][4] = {};
  gemm_core256(A, B, Ktot, m0, n0, Alds, Blds, acc0, acc1);

  const int lane = threadIdx.x & 63, wid = threadIdx.x >> 6;
  const int wm = wid >> 2, wn = wid & 3;
#pragma unroll
  for (int i = 0; i < 8; ++i) {
    const int rowg = m0 + wm * 128 + i * 16 + ((lane >> 4) * 4);
    float b0 = 0.f, b1 = 0.f, b2 = 0.f, b3 = 0.f;
    if (biasMode == 1) {
      const float4 bv = *(const float4*)(bias + rowg);
      b0 = bv.x; b1 = bv.y; b2 = bv.z; b3 = bv.w;
    }
#pragma unroll
    for (int j = 0; j < 4; ++j) {
      const int colg = n0 + wn * 64 + j * 16 + (lane & 15);
      const float bc = (biasMode == 2) ? bias[colg] : 0.0f;
      const f32x4 v = (i < 4) ? acc0[i][j] : acc1[i - 4][j];
      ushort4 st;
      st.x = f2bf(v[0] * scale + b0 + bc);
      st.y = f2bf(v[1] * scale + b1 + bc);
      st.z = f2bf(v[2] * scale + b2 + bc);
      st.w = f2bf(v[3] * scale + b3 + bc);
      *(ushort4*)(O + (size_t)colg * LDC + rowg) = st;
    }
  }
}

// fused QKV: A = Wt rows o in [0,1536) (Wq|Wk|Wv stacked), B = Hn[z], K=512.
// o-tile is 256-wide and 512%256==0 -> each block belongs to exactly one matrix.
// Q/K: Out[n][o&511] (ushort4, contiguous). V: Vt[o][n] transposed (scalar u16,
// lanes 0..15 have consecutive n -> 32B-contiguous runs).
__global__ __launch_bounds__(512, 2) void gemm_qkv(
    const u16* __restrict__ Wt, const u16* __restrict__ Hn,
    u16* __restrict__ Qb, u16* __restrict__ Kb, u16* __restrict__ Vt,
    const float* __restrict__ bq, const float* __restrict__ bk,
    const float* __restrict__ bv) {
  __shared__ u16 Alds[2 * 256 * 64];
  __shared__ u16 Blds[2 * 256 * 64];
  const uint3 bid = remap_xcd();
  const int z = bid.z;
  const u16* B = Hn + (size_t)z * ((size_t)N_ * C_);
  const int m0 = bid.y * 256;    // o in [0,1536)
  const int n0 = bid.x * 256;    // n
  f32x4 acc0[4][4] = {};
  f32x4 acc1[4][4] = {};
  gemm_core256(Wt, B, 512, m0, n0, Alds, Blds, acc0, acc1);

  const int lane = threadIdx.x & 63, wid = threadIdx.x >> 6;
  const int wm = wid >> 2, wn = wid & 3;
  const int mat = m0 >> 9;       // 0:Q 1:K 2:V (block-uniform)
  const float* bias = (mat == 0) ? bq : (mat == 1) ? bk : bv;
  u16* O  = ((mat == 0) ? Qb : Kb) + (size_t)z * ((size_t)N_ * C_);
  u16* Vz = Vt + (size_t)z * ((size_t)N_ * C_);
#pragma unroll
  for (int i = 0; i < 8; ++i) {
    const int rowg = m0 + wm * 128 + i * 16 + ((lane >> 4) * 4);
    const int o = rowg & 511;
    const float4 bvv = *(const float4*)(bias + o);
#pragma unroll
    for (int j = 0; j < 4; ++j) {
      const int colg = n0 + wn * 64 + j * 16 + (lane & 15);
      const f32x4 v = (i < 4) ? acc0[i][j] : acc1[i - 4][j];
      if (mat < 2) {
        ushort4 st;
        st.x = f2bf(v[0] + bvv.x);
        st.y = f2bf(v[1] + bvv.y);
        st.z = f2bf(v[2] + bvv.z);
        st.w = f2bf(v[3] + bvv.w);
        *(ushort4*)(O + (size_t)colg * 512 + o) = st;
      } else {
        Vz[(size_t)(o + 0) * N_ + colg] = f2bf(v[0] + bvv.x);
        Vz[(size_t)(o + 1) * N_ + colg] = f2bf(v[1] + bvv.y);
        Vz[(size_t)(o + 2) * N_ + colg] = f2bf(v[2] + bvv.z);
        Vz[(size_t)(o + 3) * N_ + colg] = f2bf(v[3] + bvv.w);
      }
    }
  }
}

// final: D[n][o] = sum_c H2[n][c]*Wnt[o][c]; out[b][o][n] = x + D + bn[o]  (fp32)
__global__ __launch_bounds__(512, 2) void gemm_bt_final(
    const u16* __restrict__ A, const u16* __restrict__ Bw,
    const float* __restrict__ x, const float* __restrict__ bn,
    float* __restrict__ Out, int Ktot) {
  __shared__ u16 Alds[2 * 256 * 64];
  __shared__ u16 Blds[2 * 256 * 64];
  const uint3 bid = remap_xcd();
  const int z = bid.z;
  const u16*   Ab = A + (size_t)z * ((size_t)N_ * C_);
  const float* xb = x + (size_t)z * ((size_t)C_ * N_);
  float*       Ob = Out + (size_t)z * ((size_t)C_ * N_);
  const int m0 = bid.y * 256, n0 = bid.x * 256;
  f32x4 acc0[4][4] = {};
  f32x4 acc1[4][4] = {};
  gemm_core256(Ab, Bw, Ktot, m0, n0, Alds, Blds, acc0, acc1);

  const int lane = threadIdx.x & 63, wid = threadIdx.x >> 6;
  const int wm = wid >> 2, wn = wid & 3;
#pragma unroll
  for (int i = 0; i < 8; ++i) {
    const int rowg = m0 + wm * 128 + i * 16 + ((lane >> 4) * 4);   // n
#pragma unroll
    for (int j = 0; j < 4; ++j) {
      const int colg = n0 + wn * 64 + j * 16 + (lane & 15);        // o
      const float bc = bn[colg];
      const size_t off = (size_t)colg * N_ + rowg;
      const float4 xv = *(const float4*)(xb + off);
      const f32x4 v = (i < 4) ? acc0[i][j] : acc1[i - 4][j];
      float4 ov;
      ov.x = xv.x + v[0] + bc;
      ov.y = xv.y + v[1] + bc;
      ov.z = xv.z + v[2] + bc;
      ov.w = xv.w + v[3] + bc;
      *(float4*)(Ob + off) = ov;
    }
  }
}

// ---------------- row softmax in-place on bf16 P[b*N+n][1024] ----------------
__global__ __launch_bounds__(256) void softmax_rows(u16* __restrict__ P) {
  __shared__ float red[8];
  u16* p = P + (size_t)blockIdx.x * 1024;
  const int tid = threadIdx.x;
  const ushort4 u = ((const ushort4*)p)[tid];
  const float v0 = bf2f(u.x), v1 = bf2f(u.y), v2 = bf2f(u.z), v3 = bf2f(u.w);
  float m = fmaxf(fmaxf(v0, v1), fmaxf(v2, v3));
#pragma unroll
  for (int o = 32; o; o >>= 1) m = fmaxf(m, __shfl_xor(m, o));
  const int lane = tid & 63, w = tid >> 6;
  if (lane == 0) red[w] = m;
  __syncthreads();
  m = fmaxf(fmaxf(red[0], red[1]), fmaxf(red[2], red[3]));
  const float e0 = __expf(v0 - m), e1 = __expf(v1 - m),
              e2 = __expf(v2 - m), e3 = __expf(v3 - m);
  float s = e0 + e1 + e2 + e3;
#pragma unroll
  for (int o = 32; o; o >>= 1) s += __shfl_xor(s, o);
  if (lane == 0) red[4 + w] = s;
  __syncthreads();
  s = red[4] + red[5] + red[6] + red[7];
  const float inv = 1.0f / s;
  ushort4 o4;
  o4.x = f2bf(e0 * inv); o4.y = f2bf(e1 * inv);
  o4.z = f2bf(e2 * inv); o4.w = f2bf(e3 * inv);
  ((ushort4*)p)[tid] = o4;
}

__global__ void sentinel_kernel(float* out, int n, float v) {
  const int i = blockIdx.x * blockDim.x + threadIdx.x;
  if (i < n) out[i] = v;
}

extern "C" void kernel_launch(void* const* d_in, const int* in_sizes, int n_in,
                              void* d_out, int out_size, void* d_ws, size_t ws_size,
                              hipStream_t stream) {
  const float* x  = (const float*)d_in[0];
  const float* Wq = (const float*)d_in[1];
  const float* bq = (const float*)d_in[2];
  const float* Wk = (const float*)d_in[3];
  const float* bk = (const float*)d_in[4];
  const float* Wv = (const float*)d_in[5];
  const float* bv = (const float*)d_in[6];
  const float* Wn = (const float*)d_in[7];
  const float* bn = (const float*)d_in[8];
  float* out = (float*)d_out;

  char* ws = (char*)d_ws;
  size_t off = 0;
  u16* Wt = (u16*)(ws + off);      off += (size_t)4 * 512 * 512 * 2;   // bf16 W^T x4 (Q|K|V|N)
  const size_t bnc = (size_t)B_ * N_ * C_;
  u16* Hn = (u16*)(ws + off); off += bnc * 2;          // [b][n][c]
  u16* Qb = (u16*)(ws + off); off += bnc * 2;          // [b][n][c]
  u16* Kb = (u16*)(ws + off); off += bnc * 2;          // [b][m][c]
  u16* Vt = (u16*)(ws + off); off += bnc * 2;          // [b][c][m]
  u16* P  = (u16*)(ws + off); off += (size_t)B_ * N_ * N_ * 2;  // [b][n][m]
  u16* H2 = (u16*)(ws + off); off += bnc * 2;          // [b][n][c]

  if (ws_size < off) {
    const float v = 1.0e6f + (float)(ws_size >> 20);   // absmax ~ 1e6+MB -> diagnosable
    sentinel_kernel<<<(out_size + 255) / 256, 256, 0, stream>>>(out, out_size, v);
    return;
  }

  wt_kernel<<<dim3(8, 8, 4), 256, 0, stream>>>(Wq, Wk, Wv, Wn, Wt);
  gn_fused<<<B_ * G_, 256, 0, stream>>>(x, Hn);

  const long long sNC = (long long)N_ * C_;
  const long long sNN = (long long)N_ * N_;
  // fused QKV: o-rows [0,1536) of Wt vs Hn; writes Qb[n][o], Kb[n][o], Vt[o][n]+biases
  gemm_qkv<<<dim3(4, 6, B_), 512, 0, stream>>>(Wt, Hn, Qb, Kb, Vt, bq, bk, bv);
  // S[n][m]: A=K (rows m, M'=1024), B=Q (rows n, N'=1024), K-dim=512, scaled
  gemm_bt<<<dim3(4, 4, B_), 512, 0, stream>>>(Kb, sNC, Qb, sNC, P, sNN, 512, 1024, kScale, nullptr, 0);
  softmax_rows<<<B_ * N_, 256, 0, stream>>>(P);
  // H2[n][c]: A=Vt (rows c, M'=512), B=P (rows n, N'=1024), K-dim=1024
  gemm_bt<<<dim3(4, 2, B_), 512, 0, stream>>>(Vt, sNC, P, sNN, H2, sNC, 1024, 512, 1.0f, nullptr, 0);
  // out[o][n] = x + H2·Wn^T + bn
  gemm_bt_final<<<dim3(2, 4, B_), 512, 0, stream>>>(H2, Wt + 3 * 262144, x, bn, out, 512);
}

// Round 6
// 262.551 us; speedup vs baseline: 1.5153x; 1.0473x over previous
//
#include <hip/hip_runtime.h>
#include <cstdint>

#define B_   32
#define C_   512
#define N_   1024
#define G_   32
#define CG_  16

typedef unsigned short u16;

static constexpr float kEps   = 1e-5f;
static constexpr float kScale = 0.04419417382415922f;  // 512^-0.5

using f32x4  = __attribute__((ext_vector_type(4))) float;
using short8 = __attribute__((ext_vector_type(8))) short;

__device__ __forceinline__ u16 f2bf(float f) {
  uint32_t u = __builtin_bit_cast(uint32_t, f);
  u += 0x7fffu + ((u >> 16) & 1u);   // RNE
  return (u16)(u >> 16);
}
__device__ __forceinline__ float bf2f(u16 h) {
  return __builtin_bit_cast(float, (uint32_t)h << 16);
}

// async global->LDS, 16B per lane. LDS dest is wave-uniform base (HW adds lane*16).
__device__ __forceinline__ void gload16(const void* g, void* lds) {
  __builtin_amdgcn_global_load_lds(
      (__attribute__((address_space(1))) void*)(uintptr_t)g,
      (__attribute__((address_space(3))) void*)(uint32_t)(uintptr_t)lds,
      16, 0, 0);
}

// bijective XCD-chunked remap (m204): contiguous logical chunk per XCD.
__device__ __forceinline__ uint3 remap_xcd() {
  const int gx = gridDim.x, gy = gridDim.y, gz = gridDim.z;
  const int nwg = gx * gy * gz;
  const int lin = blockIdx.x + gx * (blockIdx.y + gy * blockIdx.z);
  const int q = nwg >> 3, r = nwg & 7;
  const int xcd = lin & 7, pos = lin >> 3;
  int nid = (xcd < r ? xcd * (q + 1) : r * (q + 1) + (xcd - r) * q) + pos;
  uint3 o;
  o.x = nid % gx; nid /= gx;
  o.y = nid % gy; o.z = nid / gy;
  return o;
}

// ---------------- weights: Wt[m][o][c] = bf16(W[c][o]), LDS tile transpose ----------------
__global__ __launch_bounds__(256) void wt_kernel(
    const float* __restrict__ Wq, const float* __restrict__ Wk,
    const float* __restrict__ Wv, const float* __restrict__ Wn,
    u16* __restrict__ Wt) {
  __shared__ float tile[64][65];
  const int m = blockIdx.z;
  const int c0 = blockIdx.y * 64, o0 = blockIdx.x * 64;
  const float* W = (m == 0) ? Wq : (m == 1) ? Wk : (m == 2) ? Wv : Wn;
  const int tx = threadIdx.x & 15, ty = threadIdx.x >> 4;
#pragma unroll
  for (int rr = 0; rr < 64; rr += 16) {
    const int c = c0 + ty + rr;
    const float4 v = *(const float4*)(W + (size_t)c * 512 + o0 + tx * 4);
    tile[ty + rr][tx * 4 + 0] = v.x;
    tile[ty + rr][tx * 4 + 1] = v.y;
    tile[ty + rr][tx * 4 + 2] = v.z;
    tile[ty + rr][tx * 4 + 3] = v.w;
  }
  __syncthreads();
#pragma unroll
  for (int rr = 0; rr < 64; rr += 16) {
    const int o = o0 + ty + rr;
    ushort4 st;
    st.x = f2bf(tile[tx * 4 + 0][ty + rr]);
    st.y = f2bf(tile[tx * 4 + 1][ty + rr]);
    st.z = f2bf(tile[tx * 4 + 2][ty + rr]);
    st.w = f2bf(tile[tx * 4 + 3][ty + rr]);
    *(ushort4*)(Wt + (size_t)m * 262144 + (size_t)o * 512 + c0 + tx * 4) = st;
  }
}

// ---------------- fused groupnorm: one pass over x, stats + normalize + transpose ------
__global__ __launch_bounds__(256) void gn_fused(const float* __restrict__ x,
                                                u16* __restrict__ Hn) {
  __shared__ float lds[16 * 1028];
  __shared__ float red[10];
  const int bg = blockIdx.x, b = bg >> 5, g = bg & 31;
  const int t = threadIdx.x;
  const float4* p4 = (const float4*)(x + (size_t)bg * 16384);
  float s = 0.f, s2 = 0.f;
  for (int i = t; i < 4096; i += 256) {
    const float4 v = p4[i];
    const int e = i * 4, ic = e >> 10, n = e & 1023;
    *(float4*)(lds + ic * 1028 + n) = v;
    s  += v.x + v.y + v.z + v.w;
    s2 += v.x * v.x + v.y * v.y + v.z * v.z + v.w * v.w;
  }
#pragma unroll
  for (int o = 32; o; o >>= 1) { s += __shfl_xor(s, o); s2 += __shfl_xor(s2, o); }
  const int lane = t & 63, w = t >> 6;
  if (lane == 0) { red[w] = s; red[4 + w] = s2; }
  __syncthreads();
  if (t == 0) {
    s  = red[0] + red[1] + red[2] + red[3];
    s2 = red[4] + red[5] + red[6] + red[7];
    const float inv = 1.0f / 16384.0f;
    const float mean = s * inv;
    const float var  = s2 * inv - mean * mean;
    red[8] = mean;
    red[9] = rsqrtf(var + kEps);
  }
  __syncthreads();
  const float mean = red[8], rstd = red[9];
#pragma unroll
  for (int r = 0; r < 4; ++r) {
    const int n = t + 256 * r;
    ushort o8[16];
#pragma unroll
    for (int ic = 0; ic < 16; ++ic)
      o8[ic] = f2bf((lds[ic * 1028 + n] - mean) * rstd);
    u16* dst = Hn + ((size_t)(b * N_ + n)) * C_ + g * 16;
#pragma unroll
    for (int q = 0; q < 4; ++q) {
      ushort4 st; st.x = o8[q*4]; st.y = o8[q*4+1]; st.z = o8[q*4+2]; st.w = o8[q*4+3];
      *(ushort4*)(dst + q * 4) = st;
    }
  }
}

// ---------------- GEMM core v6: 256x256 tile, BK=64, 8 waves (2Mx4N), dbuf LDS,
// 4 phases/K-tile with REGISTER-PIPELINED fragment reads (one phase ahead, static
// sets aX/aY/bX/bY), counted lgkmcnt, one barrier per phase, XOR-swizzle both sides.
// Boundary: lgkm(0)+vmcnt(0) BEFORE the ph3 barrier (cross-wave stage-complete proof),
// next-tile reads issued after it hide under ph3's MFMA.
#define LDA_(D, BASE, MH, PC)                                                   \
  _Pragma("unroll")                                                             \
  for (int i_ = 0; i_ < 4; ++i_)                                                \
    D[i_] = *(const short8*)((BASE) + (wm * 128 + (MH) * 64 + i_ * 16 + arow) * 128 + (PC));
#define LDB_(D, BASE, PC)                                                       \
  _Pragma("unroll")                                                             \
  for (int j_ = 0; j_ < 4; ++j_)                                                \
    D[j_] = *(const short8*)((BASE) + (wn * 64 + j_ * 16 + arow) * 128 + (PC));
#define MM_(ACC, AA, BB)                                                        \
  __builtin_amdgcn_s_setprio(1);                                                \
  _Pragma("unroll")                                                             \
  for (int i_ = 0; i_ < 4; ++i_)                                                \
    _Pragma("unroll")                                                           \
    for (int j_ = 0; j_ < 4; ++j_)                                              \
      ACC[i_][j_] = __builtin_amdgcn_mfma_f32_16x16x32_bf16(AA[i_], BB[j_], ACC[i_][j_], 0, 0, 0); \
  __builtin_amdgcn_s_setprio(0);

__device__ __forceinline__ void gemm_core256(
    const u16* __restrict__ A, const u16* __restrict__ B,
    int Ktot, int m0, int n0,
    u16* Alds, u16* Blds, f32x4 acc0[4][4], f32x4 acc1[4][4]) {
  const int tid = threadIdx.x, lane = tid & 63, wid = tid >> 6;
  const int wm = wid >> 2, wn = wid & 3;

  const int sr  = lane >> 3;
  const int scb = (lane & 7) ^ sr;             // pre-swizzled source 16B-block
  const u16* Ag = A + (size_t)(m0 + wid * 32 + sr) * Ktot + scb * 8;
  const u16* Bg = B + (size_t)(n0 + wid * 32 + sr) * Ktot + scb * 8;
  char* Al = (char*)Alds + wid * 4096;
  char* Bl = (char*)Blds + wid * 4096;
  const long long r8 = (long long)8 * Ktot;    // 8 rows in elements

  const int arow = lane & 15, g4 = lane >> 4, rx = lane & 7;
  const int pc0 = (g4 ^ rx) * 16;              // kk0 swizzled phys byte col
  const int pc1 = ((4 + g4) ^ rx) * 16;        // kk1
  const int nt = Ktot >> 6;

  // prologue: stage tile 0 into buf 0, drain, preload ph0 fragments
#pragma unroll
  for (int g = 0; g < 4; ++g) {
    gload16(Ag + g * r8, Al + g * 1024);
    gload16(Bg + g * r8, Bl + g * 1024);
  }
  asm volatile("s_waitcnt vmcnt(0)" ::: "memory");
  __builtin_amdgcn_s_barrier();
  short8 aX[4], aY[4], bX[4], bY[4];
  LDA_(aX, (const char*)Alds, 0, pc0);
  LDB_(bX, (const char*)Blds, pc0);

  for (int t = 0; t < nt; ++t) {
    const int cur = t & 1;
    const char* Ab = (const char*)Alds + cur * 32768;
    const char* Bb = (const char*)Blds + cur * 32768;
    const char* An = (const char*)Alds + (cur ^ 1) * 32768;
    const char* Bn = (const char*)Blds + (cur ^ 1) * 32768;
    char* Aln = Al + (cur ^ 1) * 32768;
    char* Bln = Bl + (cur ^ 1) * 32768;
    const bool nx = (t + 1 < nt);
    const long long ko = (long long)(t + 1) * 64;

    // ---- ph0: MFMA(aX,bX)->acc0 ; stage next-B ; prefetch aY (ph1)
    if (nx) {
#pragma unroll
      for (int g = 0; g < 4; ++g) gload16(Bg + ko + g * r8, Bln + g * 1024);
    }
    LDA_(aY, Ab, 1, pc0);
    asm volatile("s_waitcnt lgkmcnt(4)" ::: "memory");   // aX,bX done; aY in flight
    __builtin_amdgcn_sched_barrier(0);
    __builtin_amdgcn_s_barrier();
    MM_(acc0, aX, bX);

    // ---- ph1: MFMA(aY,bX)->acc1 ; stage next-A ; prefetch aX,bY (ph2)
    if (nx) {
#pragma unroll
      for (int g = 0; g < 4; ++g) gload16(Ag + ko + g * r8, Aln + g * 1024);
    }
    LDA_(aX, Ab, 0, pc1);
    LDB_(bY, Bb, pc1);
    asm volatile("s_waitcnt lgkmcnt(8)" ::: "memory");   // aY done; aX,bY in flight
    __builtin_amdgcn_sched_barrier(0);
    __builtin_amdgcn_s_barrier();
    MM_(acc1, aY, bX);

    // ---- ph2: MFMA(aX,bY)->acc0 ; prefetch aY (ph3)
    LDA_(aY, Ab, 1, pc1);
    asm volatile("s_waitcnt lgkmcnt(4)" ::: "memory");   // aX,bY done; aY in flight
    __builtin_amdgcn_sched_barrier(0);
    __builtin_amdgcn_s_barrier();
    MM_(acc0, aX, bY);

    // ---- ph3: boundary sync, then MFMA(aY,bY)->acc1 with next-tile reads under it
    asm volatile("s_waitcnt lgkmcnt(0)" ::: "memory");   // aY done (all reads drained)
    if (nx) {
      asm volatile("s_waitcnt vmcnt(0)" ::: "memory");   // own 8 stage loads landed
    }
    __builtin_amdgcn_sched_barrier(0);
    __builtin_amdgcn_s_barrier();                        // ALL waves: reads drained + stages landed
    if (nx) {
      LDA_(aX, An, 0, pc0);                              // next-tile ph0 frags, hide under MFMA
      LDB_(bX, Bn, pc0);
    }
    MM_(acc1, aY, bY);
  }
}

// D fragment mapping (m89-verified): col = lane&15, row = (lane>>4)*4 + reg.
__global__ __launch_bounds__(512, 2) void gemm_bt(
    const u16* __restrict__ A, long long sAz,
    const u16* __restrict__ B, long long sBz,
    u16* __restrict__ Out, long long sOz,
    int Ktot, int LDC, float scale,
    const float* __restrict__ bias, int biasMode) {
  __shared__ u16 Alds[2 * 256 * 64];
  __shared__ u16 Blds[2 * 256 * 64];
  const uint3 bid = remap_xcd();
  const int z = bid.z;
  A += (size_t)z * sAz;
  B += (size_t)z * sBz;
  u16* O = Out + (size_t)z * sOz;
  const int m0 = bid.y * 256, n0 = bid.x * 256;
  f32x4 acc0[4][4] = {};
  f32x4 acc1[4][4] = {};
  gemm_core256(A, B, Ktot, m0, n0, Alds, Blds, acc0, acc1);

  const int lane = threadIdx.x & 63, wid = threadIdx.x >> 6;
  const int wm = wid >> 2, wn = wid & 3;
#pragma unroll
  for (int i = 0; i < 8; ++i) {
    const int rowg = m0 + wm * 128 + i * 16 + ((lane >> 4) * 4);
    float b0 = 0.f, b1 = 0.f, b2 = 0.f, b3 = 0.f;
    if (biasMode == 1) {
      const float4 bv = *(const float4*)(bias + rowg);
      b0 = bv.x; b1 = bv.y; b2 = bv.z; b3 = bv.w;
    }
#pragma unroll
    for (int j = 0; j < 4; ++j) {
      const int colg = n0 + wn * 64 + j * 16 + (lane & 15);
      const float bc = (biasMode == 2) ? bias[colg] : 0.0f;
      const f32x4 v = (i < 4) ? acc0[i][j] : acc1[i - 4][j];
      ushort4 st;
      st.x = f2bf(v[0] * scale + b0 + bc);
      st.y = f2bf(v[1] * scale + b1 + bc);
      st.z = f2bf(v[2] * scale + b2 + bc);
      st.w = f2bf(v[3] * scale + b3 + bc);
      *(ushort4*)(O + (size_t)colg * LDC + rowg) = st;
    }
  }
}

// fused QKV: A = Wt rows o in [0,1536) (Wq|Wk|Wv stacked), B = Hn[z], K=512.
__global__ __launch_bounds__(512, 2) void gemm_qkv(
    const u16* __restrict__ Wt, const u16* __restrict__ Hn,
    u16* __restrict__ Qb, u16* __restrict__ Kb, u16* __restrict__ Vt,
    const float* __restrict__ bq, const float* __restrict__ bk,
    const float* __restrict__ bv) {
  __shared__ u16 Alds[2 * 256 * 64];
  __shared__ u16 Blds[2 * 256 * 64];
  const uint3 bid = remap_xcd();
  const int z = bid.z;
  const u16* B = Hn + (size_t)z * ((size_t)N_ * C_);
  const int m0 = bid.y * 256;    // o in [0,1536)
  const int n0 = bid.x * 256;    // n
  f32x4 acc0[4][4] = {};
  f32x4 acc1[4][4] = {};
  gemm_core256(Wt, B, 512, m0, n0, Alds, Blds, acc0, acc1);

  const int lane = threadIdx.x & 63, wid = threadIdx.x >> 6;
  const int wm = wid >> 2, wn = wid & 3;
  const int mat = m0 >> 9;       // 0:Q 1:K 2:V (block-uniform)
  const float* bias = (mat == 0) ? bq : (mat == 1) ? bk : bv;
  u16* O  = ((mat == 0) ? Qb : Kb) + (size_t)z * ((size_t)N_ * C_);
  u16* Vz = Vt + (size_t)z * ((size_t)N_ * C_);
#pragma unroll
  for (int i = 0; i < 8; ++i) {
    const int rowg = m0 + wm * 128 + i * 16 + ((lane >> 4) * 4);
    const int o = rowg & 511;
    const float4 bvv = *(const float4*)(bias + o);
#pragma unroll
    for (int j = 0; j < 4; ++j) {
      const int colg = n0 + wn * 64 + j * 16 + (lane & 15);
      const f32x4 v = (i < 4) ? acc0[i][j] : acc1[i - 4][j];
      if (mat < 2) {
        ushort4 st;
        st.x = f2bf(v[0] + bvv.x);
        st.y = f2bf(v[1] + bvv.y);
        st.z = f2bf(v[2] + bvv.z);
        st.w = f2bf(v[3] + bvv.w);
        *(ushort4*)(O + (size_t)colg * 512 + o) = st;
      } else {
        Vz[(size_t)(o + 0) * N_ + colg] = f2bf(v[0] + bvv.x);
        Vz[(size_t)(o + 1) * N_ + colg] = f2bf(v[1] + bvv.y);
        Vz[(size_t)(o + 2) * N_ + colg] = f2bf(v[2] + bvv.z);
        Vz[(size_t)(o + 3) * N_ + colg] = f2bf(v[3] + bvv.w);
      }
    }
  }
}

// final: D[n][o] = sum_c H2[n][c]*Wnt[o][c]; out[b][o][n] = x + D + bn[o]  (fp32)
__global__ __launch_bounds__(512, 2) void gemm_bt_final(
    const u16* __restrict__ A, const u16* __restrict__ Bw,
    const float* __restrict__ x, const float* __restrict__ bn,
    float* __restrict__ Out, int Ktot) {
  __shared__ u16 Alds[2 * 256 * 64];
  __shared__ u16 Blds[2 * 256 * 64];
  const uint3 bid = remap_xcd();
  const int z = bid.z;
  const u16*   Ab = A + (size_t)z * ((size_t)N_ * C_);
  const float* xb = x + (size_t)z * ((size_t)C_ * N_);
  float*       Ob = Out + (size_t)z * ((size_t)C_ * N_);
  const int m0 = bid.y * 256, n0 = bid.x * 256;
  f32x4 acc0[4][4] = {};
  f32x4 acc1[4][4] = {};
  gemm_core256(Ab, Bw, Ktot, m0, n0, Alds, Blds, acc0, acc1);

  const int lane = threadIdx.x & 63, wid = threadIdx.x >> 6;
  const int wm = wid >> 2, wn = wid & 3;
#pragma unroll
  for (int i = 0; i < 8; ++i) {
    const int rowg = m0 + wm * 128 + i * 16 + ((lane >> 4) * 4);   // n
#pragma unroll
    for (int j = 0; j < 4; ++j) {
      const int colg = n0 + wn * 64 + j * 16 + (lane & 15);        // o
      const float bc = bn[colg];
      const size_t off = (size_t)colg * N_ + rowg;
      const float4 xv = *(const float4*)(xb + off);
      const f32x4 v = (i < 4) ? acc0[i][j] : acc1[i - 4][j];
      float4 ov;
      ov.x = xv.x + v[0] + bc;
      ov.y = xv.y + v[1] + bc;
      ov.z = xv.z + v[2] + bc;
      ov.w = xv.w + v[3] + bc;
      *(float4*)(Ob + off) = ov;
    }
  }
}

// ---------------- row softmax in-place on bf16 P[b*N+n][1024] ----------------
__global__ __launch_bounds__(256) void softmax_rows(u16* __restrict__ P) {
  __shared__ float red[8];
  u16* p = P + (size_t)blockIdx.x * 1024;
  const int tid = threadIdx.x;
  const ushort4 u = ((const ushort4*)p)[tid];
  const float v0 = bf2f(u.x), v1 = bf2f(u.y), v2 = bf2f(u.z), v3 = bf2f(u.w);
  float m = fmaxf(fmaxf(v0, v1), fmaxf(v2, v3));
#pragma unroll
  for (int o = 32; o; o >>= 1) m = fmaxf(m, __shfl_xor(m, o));
  const int lane = tid & 63, w = tid >> 6;
  if (lane == 0) red[w] = m;
  __syncthreads();
  m = fmaxf(fmaxf(red[0], red[1]), fmaxf(red[2], red[3]));
  const float e0 = __expf(v0 - m), e1 = __expf(v1 - m),
              e2 = __expf(v2 - m), e3 = __expf(v3 - m);
  float s = e0 + e1 + e2 + e3;
#pragma unroll
  for (int o = 32; o; o >>= 1) s += __shfl_xor(s, o);
  if (lane == 0) red[4 + w] = s;
  __syncthreads();
  s = red[4] + red[5] + red[6] + red[7];
  const float inv = 1.0f / s;
  ushort4 o4;
  o4.x = f2bf(e0 * inv); o4.y = f2bf(e1 * inv);
  o4.z = f2bf(e2 * inv); o4.w = f2bf(e3 * inv);
  ((ushort4*)p)[tid] = o4;
}

__global__ void sentinel_kernel(float* out, int n, float v) {
  const int i = blockIdx.x * blockDim.x + threadIdx.x;
  if (i < n) out[i] = v;
}

extern "C" void kernel_launch(void* const* d_in, const int* in_sizes, int n_in,
                              void* d_out, int out_size, void* d_ws, size_t ws_size,
                              hipStream_t stream) {
  const float* x  = (const float*)d_in[0];
  const float* Wq = (const float*)d_in[1];
  const float* bq = (const float*)d_in[2];
  const float* Wk = (const float*)d_in[3];
  const float* bk = (const float*)d_in[4];
  const float* Wv = (const float*)d_in[5];
  const float* bv = (const float*)d_in[6];
  const float* Wn = (const float*)d_in[7];
  const float* bn = (const float*)d_in[8];
  float* out = (float*)d_out;

  char* ws = (char*)d_ws;
  size_t off = 0;
  u16* Wt = (u16*)(ws + off);      off += (size_t)4 * 512 * 512 * 2;   // bf16 W^T x4 (Q|K|V|N)
  const size_t bnc = (size_t)B_ * N_ * C_;
  u16* Hn = (u16*)(ws + off); off += bnc * 2;          // [b][n][c]
  u16* Qb = (u16*)(ws + off); off += bnc * 2;          // [b][n][c]
  u16* Kb = (u16*)(ws + off); off += bnc * 2;          // [b][m][c]
  u16* Vt = (u16*)(ws + off); off += bnc * 2;          // [b][c][m]
  u16* P  = (u16*)(ws + off); off += (size_t)B_ * N_ * N_ * 2;  // [b][n][m]
  u16* H2 = (u16*)(ws + off); off += bnc * 2;          // [b][n][c]

  if (ws_size < off) {
    const float v = 1.0e6f + (float)(ws_size >> 20);   // absmax ~ 1e6+MB -> diagnosable
    sentinel_kernel<<<(out_size + 255) / 256, 256, 0, stream>>>(out, out_size, v);
    return;
  }

  wt_kernel<<<dim3(8, 8, 4), 256, 0, stream>>>(Wq, Wk, Wv, Wn, Wt);
  gn_fused<<<B_ * G_, 256, 0, stream>>>(x, Hn);

  const long long sNC = (long long)N_ * C_;
  const long long sNN = (long long)N_ * N_;
  // fused QKV: o-rows [0,1536) of Wt vs Hn; writes Qb[n][o], Kb[n][o], Vt[o][n]+biases
  gemm_qkv<<<dim3(4, 6, B_), 512, 0, stream>>>(Wt, Hn, Qb, Kb, Vt, bq, bk, bv);
  // S[n][m]: A=K (rows m, M'=1024), B=Q (rows n, N'=1024), K-dim=512, scaled
  gemm_bt<<<dim3(4, 4, B_), 512, 0, stream>>>(Kb, sNC, Qb, sNC, P, sNN, 512, 1024, kScale, nullptr, 0);
  softmax_rows<<<B_ * N_, 256, 0, stream>>>(P);
  // H2[n][c]: A=Vt (rows c, M'=512), B=P (rows n, N'=1024), K-dim=1024
  gemm_bt<<<dim3(4, 2, B_), 512, 0, stream>>>(Vt, sNC, P, sNN, H2, sNC, 1024, 512, 1.0f, nullptr, 0);
  // out[o][n] = x + H2·Wn^T + bn
  gemm_bt_final<<<dim3(2, 4, B_), 512, 0, stream>>>(H2, Wt + 3 * 262144, x, bn, out, 512);
}